// Round 1
// baseline (215.920 us; speedup 1.0000x reference)
//
#include <hip/hip_runtime.h>
#include <hip/hip_bf16.h>
#include <stdint.h>

typedef unsigned short u16;
typedef short short8 __attribute__((ext_vector_type(8)));
typedef short short4v __attribute__((ext_vector_type(4)));
typedef float floatx4 __attribute__((ext_vector_type(4)));

__device__ __forceinline__ float b2f(u16 v) {
  union { unsigned int u; float f; } c; c.u = ((unsigned int)v) << 16; return c.f;
}
__device__ __forceinline__ u16 f2b(float f) {
  union { float f; unsigned int u; } c; c.f = f;
  unsigned int u = c.u;
  return (u16)((u + 0x7fffu + ((u >> 16) & 1u)) >> 16);  // RNE
}

// async global->LDS, 16B per lane. LDS dest must be wave-uniform base + lane*16.
__device__ __forceinline__ void gld_lds16(const u16* g, u16* l) {
  __builtin_amdgcn_global_load_lds(
      (const __attribute__((address_space(1))) unsigned int*)g,
      (__attribute__((address_space(3))) unsigned int*)l,
      16, 0, 0);
}

// ---------------------------------------------------------------------------
// Fused prep: x fp32->bf16 (blocks 0..6143), w_attn T (6144..6575),
// w_proj T (6576..6719). Transposes also convert fp32->bf16.
// ---------------------------------------------------------------------------
__device__ __forceinline__ void tile_transpose_f2b(
    const float* __restrict__ in, u16* __restrict__ out,
    int inRS, int outRS, int rb, int cb, int tid)
{
  __shared__ __align__(16) u16 t[64][72];
  const int r = tid >> 2, sg = tid & 3;
  const float* ip = in + (long)(rb + r) * inRS + cb + sg * 16;
#pragma unroll
  for (int i = 0; i < 16; i += 4) {
    float4 f = *(const float4*)(ip + i);
    t[r][sg * 16 + i]     = f2b(f.x);
    t[r][sg * 16 + i + 1] = f2b(f.y);
    t[r][sg * 16 + i + 2] = f2b(f.z);
    t[r][sg * 16 + i + 3] = f2b(f.w);
  }
  __syncthreads();
  short8 v0, v1;
#pragma unroll
  for (int i = 0; i < 8; i++) v0[i] = (short)t[sg * 16 + i][r];
#pragma unroll
  for (int i = 0; i < 8; i++) v1[i] = (short)t[sg * 16 + 8 + i][r];
  *(short8*)(out + (long)(cb + r) * outRS + rb + sg * 16)     = v0;
  *(short8*)(out + (long)(cb + r) * outRS + rb + sg * 16 + 8) = v1;
}

__global__ __launch_bounds__(256) void prep(
    const float* __restrict__ x, u16* __restrict__ xb,
    const float* __restrict__ w_attn, u16* __restrict__ wTa,
    const float* __restrict__ w_proj, u16* __restrict__ wTp)
{
  const int bid = blockIdx.x, tid = threadIdx.x;
  if (bid < 6144) {
    int i = (bid * 256 + tid) * 4;
    float4 f = *(const float4*)(x + i);
    short4v v;
    v[0] = (short)f2b(f.x); v[1] = (short)f2b(f.y);
    v[2] = (short)f2b(f.z); v[3] = (short)f2b(f.w);
    *(short4v*)(xb + i) = v;
  } else if (bid < 6576) {
    int t = bid - 6144;                 // 36 x 12 tiles of w_attn [768][2304]
    tile_transpose_f2b(w_attn, wTa, 2304, 768, (t / 36) * 64, (t % 36) * 64, tid);
  } else {
    int t = bid - 6576;                 // 12 x 12 tiles of w_proj [768][768]
    tile_transpose_f2b(w_proj, wTp, 768, 768, (t / 12) * 64, (t % 12) * 64, tid);
  }
}

// ---------------------------------------------------------------------------
// Legacy C = A * Bt^T + bias (kept for the proj GEMM only).
// ---------------------------------------------------------------------------
__device__ __forceinline__ void store_out(u16* p, float v)  { *p = f2b(v); }
__device__ __forceinline__ void store_out(float* p, float v) { *p = v; }

template <int BM>
__device__ __forceinline__ void stage(
    const u16* __restrict__ A, const u16* __restrict__ Bt,
    long rowbase, long colbase, int K, int k0,
    u16* dA, u16* dB, int tid)
{
  const int c0 = tid, c1 = tid + 256;
  const int ar0 = c0 >> 2, ak0 = (c0 & 3) * 8;
  const int ar1 = c1 >> 2, ak1 = (c1 & 3) * 8;
  gld_lds16(A + (rowbase + ar0) * K + k0 + ak0, dA + c0 * 8);
  if (BM == 128)
    gld_lds16(A + (rowbase + ar1) * K + k0 + ak1, dA + c1 * 8);
  gld_lds16(Bt + (colbase + ar0) * K + k0 + ak0, dB + c0 * 8);
  gld_lds16(Bt + (colbase + ar1) * K + k0 + ak1, dB + c1 * 8);
}

template <typename OT, int BM, bool SPLIT>
__global__ __launch_bounds__(256) void gemm_bt_bias(
    const u16* __restrict__ A, const u16* __restrict__ Bt,
    const float* __restrict__ bias, OT* __restrict__ C, u16* __restrict__ vT,
    int M, int N, int K, int strideC)
{
  constexpr int WNF = (BM == 128) ? 4 : 2;      // n-frags per wave
  __shared__ __align__(16) u16 sA[2][BM * 32];
  __shared__ __align__(16) u16 sB[2][128 * 32];
  const int tid = threadIdx.x;
  const int lane = tid & 63;
  const int wave = tid >> 6;
  const int wm = (BM == 128) ? (wave >> 1) * 64 : 0;
  const int wn = (BM == 128) ? (wave & 1) * 64 : wave * 32;
  const int l15 = lane & 15;
  const int q = lane >> 4;
  const long rowbase = (long)blockIdx.y * BM;
  const long colbase = (long)blockIdx.x * 128;

  floatx4 acc[4][WNF];
#pragma unroll
  for (int i = 0; i < 4; i++)
#pragma unroll
    for (int j = 0; j < WNF; j++) acc[i][j] = (floatx4){0.f, 0.f, 0.f, 0.f};

  stage<BM>(A, Bt, rowbase, colbase, K, 0, sA[0], sB[0], tid);
  __syncthreads();   // buf0 ready

  const int NIT = K / 32;
  for (int it = 0; it < NIT; ++it) {
    const int cur = it & 1;
    if (it + 1 < NIT)
      stage<BM>(A, Bt, rowbase, colbase, K, (it + 1) * 32, sA[cur ^ 1], sB[cur ^ 1], tid);
    short8 af[4], bf[WNF];
#pragma unroll
    for (int mt = 0; mt < 4; mt++)
      af[mt] = *(const short8*)(sA[cur] + (wm + mt * 16 + l15) * 32 + q * 8);
#pragma unroll
    for (int nt = 0; nt < WNF; nt++)
      bf[nt] = *(const short8*)(sB[cur] + (wn + nt * 16 + l15) * 32 + q * 8);
#pragma unroll
    for (int mt = 0; mt < 4; mt++)
#pragma unroll
      for (int nt = 0; nt < WNF; nt++)
        acc[mt][nt] = __builtin_amdgcn_mfma_f32_16x16x32_bf16(af[mt], bf[nt], acc[mt][nt], 0, 0, 0);
    if (it + 1 < NIT) __syncthreads();
  }

  if (SPLIT && colbase >= 1536) {
    const long b = rowbase >> 10;
    const int t0b = (int)(rowbase & 1023) + wm;
#pragma unroll
    for (int nt = 0; nt < WNF; nt++) {
      const int col = (int)colbase + wn + nt * 16 + l15;
      const float bv = bias[col];
      const int dloc = col - 1536;
      u16* bp = vT + (b * 12 + (dloc >> 6)) * 65536L + (long)(dloc & 63) * 1024;
#pragma unroll
      for (int mt = 0; mt < 4; mt++) {
        short4v pv;
#pragma unroll
        for (int r = 0; r < 4; r++) pv[r] = (short)f2b(acc[mt][nt][r] + bv);
        *(short4v*)(bp + t0b + mt * 16 + q * 4) = pv;
      }
    }
  } else {
#pragma unroll
    for (int nt = 0; nt < WNF; nt++) {
      const long col = colbase + wn + nt * 16 + l15;
      const float bv = bias[col];
#pragma unroll
      for (int mt = 0; mt < 4; mt++)
#pragma unroll
        for (int r = 0; r < 4; r++) {
          const long row = rowbase + wm + mt * 16 + q * 4 + r;
          store_out(C + row * strideC + col, acc[mt][nt][r] + bv);
        }
    }
  }
}

// ---------------------------------------------------------------------------
// R8: qkv GEMM, deep-pipelined (T2+T3+T4+T5 stack).
// Tile 256x288, BK=32, 4 LDS slots (136 KiB), 512 thr = 8 waves (4M x 2N),
// per-wave 64x144 (4x9 frags). Grid (2304/288)x(8192/256) = 8x32 = 256 blocks
// = exactly 1 block/CU, zero scheduling-round waste.
//
// Schedule: per K-tile j (slot j&3): 2 phases x 18 MFMA with setprio(1);
// phase A stages A-panel of tile j+3, phase B stages B-panel of tile j+3
// into slot (j+3)&3 (last read at tile j-1 -> barrier-protected).
// Boundary: counted s_waitcnt vmcnt(8) (never 0 until the tail) + raw
// s_barrier. Per-thread loads per tile = 4 (A2+B2; waves 0-1 carry +1 B).
//
// LDS swizzle (T2, derived for 64B row stride): element (row,k-octet q) lives
// at row*32 + ((q ^ ((row>>1)&3))<<3). For the frag-read pattern (16 lanes,
// rows base+l15, base%16==0) banks alias exactly 2-way = free (m136).
// Inverse permutation is applied to the GLOBAL source column so that
// global_load_lds keeps its mandatory linear lane*16 destination (rule 21).
// ---------------------------------------------------------------------------
#define QKV_K 768
#define QKV_NT 24   // 768/32

__global__ __launch_bounds__(512, 2) void gemm_qkv_8ph(
    const u16* __restrict__ A, const u16* __restrict__ Bt,
    const float* __restrict__ bias, u16* __restrict__ qkOut, u16* __restrict__ vT)
{
  __shared__ __align__(16) u16 sA[4][256 * 32];   // 64 KiB
  __shared__ __align__(16) u16 sB[4][288 * 32];   // 72 KiB

  const int tid = threadIdx.x;
  const int lane = tid & 63;
  const int l15 = lane & 15, q = lane >> 4;
  const int wave = tid >> 6;
  const int wm = (wave >> 1) * 64;    // 4 M-warps: rows wm..wm+63
  const int wn = (wave & 1) * 144;    // 2 N-warps: cols wn..wn+143
  const long rowbase = (long)blockIdx.y * 256;
  const long colbase = (long)blockIdx.x * 288;
  // per-thread swizzled k-octet offset for all frag reads (key = (l15>>1)&3,
  // independent of the 16-aligned frag base)
  const int xq = ((q ^ ((l15 >> 1) & 3)) << 3);

  // staging chunk c (16B): row = c>>2, slot-octet = c&3, key = (c>>3)&3;
  // pre-swizzled global column = ((c&3) ^ ((c>>3)&3)) * 8
  const int ca0 = tid, ca1 = tid + 512;
  const u16* pa0 = A + (rowbase + (ca0 >> 2)) * QKV_K + ((((ca0 & 3) ^ ((ca0 >> 3) & 3))) << 3);
  const u16* pa1 = A + (rowbase + (ca1 >> 2)) * QKV_K + ((((ca1 & 3) ^ ((ca1 >> 3) & 3))) << 3);
  const int cb0 = tid, cb1 = tid + 512, cb2 = tid + 1024;
  const u16* pb0 = Bt + (colbase + (cb0 >> 2)) * QKV_K + ((((cb0 & 3) ^ ((cb0 >> 3) & 3))) << 3);
  const u16* pb1 = Bt + (colbase + (cb1 >> 2)) * QKV_K + ((((cb1 & 3) ^ ((cb1 >> 3) & 3))) << 3);
  const u16* pb2 = Bt + (colbase + (cb2 >> 2) - (tid < 128 ? 0 : 224)) * QKV_K
                      + ((((cb2 & 3) ^ ((cb2 >> 3) & 3))) << 3);  // clamp unused lanes in-range
  const bool b3 = (tid < 128);

#define STAGE_A(t, s) do { \
    const long k0_ = (long)(t) * 32; \
    gld_lds16(pa0 + k0_, &sA[s][ca0 * 8]); \
    gld_lds16(pa1 + k0_, &sA[s][ca1 * 8]); } while (0)
#define STAGE_B(t, s) do { \
    const long k0_ = (long)(t) * 32; \
    gld_lds16(pb0 + k0_, &sB[s][cb0 * 8]); \
    gld_lds16(pb1 + k0_, &sB[s][cb1 * 8]); \
    if (b3) gld_lds16(pb2 + k0_, &sB[s][cb2 * 8]); } while (0)

  floatx4 acc[4][9];
#pragma unroll
  for (int i = 0; i < 4; i++)
#pragma unroll
    for (int n = 0; n < 9; n++) acc[i][n] = (floatx4){0.f, 0.f, 0.f, 0.f};

  // prologue: tiles 0,1,2 -> slots 0,1,2 (per-thread 12 loads; oldest 4 = tile 0)
  STAGE_A(0, 0); STAGE_B(0, 0);
  STAGE_A(1, 1); STAGE_B(1, 1);
  STAGE_A(2, 2); STAGE_B(2, 2);
  asm volatile("s_waitcnt vmcnt(8)" ::: "memory");  // tile 0 landed
  __builtin_amdgcn_s_barrier();

#pragma unroll 4
  for (int j = 0; j < QKV_NT; ++j) {
    const int slot = j & 3;
    const u16* ap = sA[slot];
    const u16* bp = sB[slot];

    // ---- phase A: ds-reads (11), stage A of j+3, 18 MFMA ----
    short8 bf[9];
#pragma unroll
    for (int nt = 0; nt < 9; nt++)
      bf[nt] = *(const short8*)(bp + (wn + nt * 16 + l15) * 32 + xq);
    short8 a0 = *(const short8*)(ap + (wm + l15) * 32 + xq);
    short8 a1 = *(const short8*)(ap + (wm + 16 + l15) * 32 + xq);
    if (j + 3 < QKV_NT) STAGE_A(j + 3, (j + 3) & 3);
    __builtin_amdgcn_s_setprio(1);
#pragma unroll
    for (int nt = 0; nt < 9; nt++)
      acc[0][nt] = __builtin_amdgcn_mfma_f32_16x16x32_bf16(a0, bf[nt], acc[0][nt], 0, 0, 0);
#pragma unroll
    for (int nt = 0; nt < 9; nt++)
      acc[1][nt] = __builtin_amdgcn_mfma_f32_16x16x32_bf16(a1, bf[nt], acc[1][nt], 0, 0, 0);
    __builtin_amdgcn_s_setprio(0);

    // ---- phase B: ds-reads (2), stage B of j+3, 18 MFMA ----
    short8 a2 = *(const short8*)(ap + (wm + 32 + l15) * 32 + xq);
    short8 a3 = *(const short8*)(ap + (wm + 48 + l15) * 32 + xq);
    if (j + 3 < QKV_NT) STAGE_B(j + 3, (j + 3) & 3);
    __builtin_amdgcn_s_setprio(1);
#pragma unroll
    for (int nt = 0; nt < 9; nt++)
      acc[2][nt] = __builtin_amdgcn_mfma_f32_16x16x32_bf16(a2, bf[nt], acc[2][nt], 0, 0, 0);
#pragma unroll
    for (int nt = 0; nt < 9; nt++)
      acc[3][nt] = __builtin_amdgcn_mfma_f32_16x16x32_bf16(a3, bf[nt], acc[3][nt], 0, 0, 0);
    __builtin_amdgcn_s_setprio(0);

    // ---- boundary: tile j+1 must be resident; never drain to 0 mid-loop ----
    if (j < QKV_NT - 1) {
      if (j + 3 < QKV_NT)      asm volatile("s_waitcnt vmcnt(8)" ::: "memory");
      else if (j + 2 < QKV_NT) asm volatile("s_waitcnt vmcnt(4)" ::: "memory");
      else                     asm volatile("s_waitcnt vmcnt(0)" ::: "memory");
      __builtin_amdgcn_s_barrier();
    }
  }
#undef STAGE_A
#undef STAGE_B

  // ---- epilogue: cols < 1536 -> qk[row][1536]; cols >= 1536 -> vT ----
#pragma unroll
  for (int nt = 0; nt < 9; nt++) {
    const int fragc = (int)colbase + wn + nt * 16;   // lane-invariant, 16-aligned
    const int col = fragc + l15;
    const float bv = bias[col];
    if (fragc >= 1536) {
      const long bb = rowbase >> 10;
      const int dloc = col - 1536;
      u16* op = vT + (bb * 12 + (dloc >> 6)) * 65536L + (long)(dloc & 63) * 1024;
      const int t0 = (int)(rowbase & 1023) + wm;
#pragma unroll
      for (int mt = 0; mt < 4; mt++) {
        short4v pv;
#pragma unroll
        for (int r = 0; r < 4; r++) pv[r] = (short)f2b(acc[mt][nt][r] + bv);
        *(short4v*)(op + t0 + mt * 16 + q * 4) = pv;
      }
    } else {
#pragma unroll
      for (int mt = 0; mt < 4; mt++)
#pragma unroll
        for (int r = 0; r < 4; r++) {
          const long row = rowbase + wm + mt * 16 + q * 4 + r;
          qkOut[row * 1536 + col] = f2b(acc[mt][nt][r] + bv);
        }
    }
  }
}

// ---------------------------------------------------------------------------
// Flash attention, causal. One block = (b*12+h, q-tile of 64 rows), 256 thr.
// (unchanged from R5/R7 best)
// ---------------------------------------------------------------------------
__global__ __launch_bounds__(256) void attn_fwd(
    const u16* __restrict__ qk, const u16* __restrict__ vT, u16* __restrict__ y)
{
  const int bh = blockIdx.x;        // b*12 + h
  const int qt = 15 - blockIdx.y;   // reversed: long blocks dispatch first
  const int b = bh / 12, h = bh % 12;
  const long rowOff = (long)b * 1024;
  const int qb = qt * 64;

  __shared__ __align__(16) u16 sK[64 * 72];
  __shared__ __align__(16) u16 sV[2][64 * 72];  // V^T [d][key], double-buffered
  __shared__ __align__(16) u16 sP[64 * 72];     // P [qrow][key]

  const int tid = threadIdx.x;
  const int lane = tid & 63, wave = tid >> 6;
  const int l15 = lane & 15, q = lane >> 4;
  const int qrow_g = qb + wave * 16 + l15;    // this lane's softmax row

  short8 qf[2];
  {
    const u16* qp = qk + (long)(rowOff + qrow_g) * 1536 + h * 64 + q * 8;
    short8 a0 = *(const short8*)(qp);
    short8 a1 = *(const short8*)(qp + 32);
#pragma unroll
    for (int i = 0; i < 8; i++) {
      a0[i] = (short)f2b(b2f((u16)a0[i]) * 0.125f);
      a1[i] = (short)f2b(b2f((u16)a1[i]) * 0.125f);
    }
    qf[0] = a0; qf[1] = a1;
  }

  float m_i = -1e30f, l_i = 0.f;
  floatx4 o[4];
#pragma unroll
  for (int nt = 0; nt < 4; nt++) o[nt] = (floatx4){0.f, 0.f, 0.f, 0.f};

  for (int j = 0; j <= qt; j++) {
    const int jb = j * 64;
    u16* sVc = sV[j & 1];
#pragma unroll
    for (int rep = 0; rep < 2; rep++) {
      int idx = tid + rep * 256;
      int r = idx >> 3, ch = (idx & 7) * 8;
      *(short8*)(sK + r * 72 + ch) =
          *(const short8*)(qk + (long)(rowOff + jb + r) * 1536 + 768 + h * 64 + ch);
      *(short8*)(sVc + r * 72 + ch) =
          *(const short8*)(vT + (long)bh * 65536 + (long)r * 1024 + jb + ch);
    }
    __syncthreads();

    floatx4 sf[4];
#pragma unroll
    for (int mt = 0; mt < 4; mt++) sf[mt] = (floatx4){0.f, 0.f, 0.f, 0.f};
#pragma unroll
    for (int kk = 0; kk < 2; kk++) {
#pragma unroll
      for (int mt = 0; mt < 4; mt++) {
        short8 kf = *(const short8*)(sK + (mt * 16 + l15) * 72 + kk * 32 + q * 8);
        sf[mt] = __builtin_amdgcn_mfma_f32_16x16x32_bf16(kf, qf[kk], sf[mt], 0, 0, 0);
      }
    }

    float mx = m_i;
#pragma unroll
    for (int mt = 0; mt < 4; mt++)
#pragma unroll
      for (int r = 0; r < 4; r++) {
        int key_g = jb + mt * 16 + q * 4 + r;
        float v = sf[mt][r];
        if (key_g > qrow_g) v = -1e30f;
        sf[mt][r] = v;
        mx = fmaxf(mx, v);
      }
    mx = fmaxf(mx, __shfl_xor(mx, 16));
    mx = fmaxf(mx, __shfl_xor(mx, 32));
    float al = __expf(m_i - mx);
    m_i = mx;
    float rsum = 0.f;
#pragma unroll
    for (int mt = 0; mt < 4; mt++) {
      short4v pv;
#pragma unroll
      for (int r = 0; r < 4; r++) {
        float p = __expf(sf[mt][r] - mx);
        rsum += p;
        pv[r] = (short)f2b(p);
      }
      *(short4v*)(sP + (wave * 16 + l15) * 72 + mt * 16 + q * 4) = pv;
    }
    rsum += __shfl_xor(rsum, 16);
    rsum += __shfl_xor(rsum, 32);
    l_i = l_i * al + rsum;
    __syncthreads();   // sP (+ this iter's sV) visible before PV

    float al_r[4];
#pragma unroll
    for (int r = 0; r < 4; r++) al_r[r] = __shfl(al, q * 4 + r);
#pragma unroll
    for (int nt = 0; nt < 4; nt++)
#pragma unroll
      for (int r = 0; r < 4; r++) o[nt][r] *= al_r[r];
#pragma unroll
    for (int kk = 0; kk < 2; kk++) {
      short8 pf = *(const short8*)(sP + (wave * 16 + l15) * 72 + kk * 32 + q * 8);
#pragma unroll
      for (int nt = 0; nt < 4; nt++) {
        short8 vf = *(const short8*)(sVc + (nt * 16 + l15) * 72 + kk * 32 + q * 8);
        o[nt] = __builtin_amdgcn_mfma_f32_16x16x32_bf16(pf, vf, o[nt], 0, 0, 0);
      }
    }
  }

  float linv = 1.f / l_i;
  float li_r[4];
#pragma unroll
  for (int r = 0; r < 4; r++) li_r[r] = __shfl(linv, q * 4 + r);
#pragma unroll
  for (int nt = 0; nt < 4; nt++)
#pragma unroll
    for (int r = 0; r < 4; r++) {
      int row = qb + wave * 16 + q * 4 + r;
      int col = h * 64 + nt * 16 + l15;
      y[(rowOff + row) * 768 + col] = f2b(o[nt][r] * li_r[r]);
    }
}

// ---------------------------------------------------------------------------
extern "C" void kernel_launch(void* const* d_in, const int* in_sizes, int n_in,
                              void* d_out, int out_size, void* d_ws, size_t ws_size,
                              hipStream_t stream) {
  const float* x      = (const float*)d_in[0];  // [8192][768] fp32
  const float* w_attn = (const float*)d_in[1];  // [768][2304] fp32
  const float* b_attn = (const float*)d_in[2];  // [2304] fp32
  const float* w_proj = (const float*)d_in[3];  // [768][768] fp32
  const float* b_proj = (const float*)d_in[4];  // [768] fp32
  float* out = (float*)d_out;                   // [8192][768] fp32

  char* ws = (char*)d_ws;
  u16* xb   = (u16*)ws; ws += (size_t)8192 * 768 * 2;     // 12.6 MB
  u16* wTa  = (u16*)ws; ws += (size_t)2304 * 768 * 2;     //  3.5 MB
  u16* wTp  = (u16*)ws; ws += (size_t)768 * 768 * 2;      //  1.2 MB
  u16* qk   = (u16*)ws; ws += (size_t)8192 * 1536 * 2;    // 25.2 MB (Q|K)
  u16* vT   = (u16*)ws; ws += (size_t)96 * 64 * 1024 * 2; // 12.6 MB (V^T)
  u16* yatt = (u16*)ws; ws += (size_t)8192 * 768 * 2;     // 12.6 MB

  // fused prep: x->bf16 + both weight transposes
  prep<<<dim3(6720), 256, 0, stream>>>(x, xb, w_attn, wTa, w_proj, wTp);

  // qkv GEMM: 256x288 tiles, 8x32 = 256 blocks = 1/CU exactly
  gemm_qkv_8ph<<<dim3(8, 32), 512, 0, stream>>>(xb, wTa, b_attn, qk, vT);

  // flash attention (V pre-transposed; in-register softmax)
  attn_fwd<<<dim3(96, 16), 256, 0, stream>>>(qk, vT, yatt);

  // out = yatt @ w_proj + b_proj   (fp32 out, 64x128 tiles)
  gemm_bt_bias<float, 64, false><<<dim3(6, 128), 256, 0, stream>>>(
      yatt, wTp, b_proj, out, (u16*)nullptr, 8192, 768, 768, 768);
}

// Round 2
// 207.867 us; speedup vs baseline: 1.0387x; 1.0387x over previous
//
#include <hip/hip_runtime.h>
#include <hip/hip_bf16.h>
#include <stdint.h>

typedef unsigned short u16;
typedef short short8 __attribute__((ext_vector_type(8)));
typedef short short4v __attribute__((ext_vector_type(4)));
typedef float floatx4 __attribute__((ext_vector_type(4)));

__device__ __forceinline__ float b2f(u16 v) {
  union { unsigned int u; float f; } c; c.u = ((unsigned int)v) << 16; return c.f;
}
__device__ __forceinline__ u16 f2b(float f) {
  union { float f; unsigned int u; } c; c.f = f;
  unsigned int u = c.u;
  return (u16)((u + 0x7fffu + ((u >> 16) & 1u)) >> 16);  // RNE
}

// async global->LDS, 16B per lane. LDS dest must be wave-uniform base + lane*16.
__device__ __forceinline__ void gld_lds16(const u16* g, u16* l) {
  __builtin_amdgcn_global_load_lds(
      (const __attribute__((address_space(1))) unsigned int*)g,
      (__attribute__((address_space(3))) unsigned int*)l,
      16, 0, 0);
}

// ---------------------------------------------------------------------------
// Fused prep: x fp32->bf16 (blocks 0..6143), w_attn T (6144..6575),
// w_proj T (6576..6719). Transposes also convert fp32->bf16.
// ---------------------------------------------------------------------------
__device__ __forceinline__ void tile_transpose_f2b(
    const float* __restrict__ in, u16* __restrict__ out,
    int inRS, int outRS, int rb, int cb, int tid)
{
  __shared__ __align__(16) u16 t[64][72];
  const int r = tid >> 2, sg = tid & 3;
  const float* ip = in + (long)(rb + r) * inRS + cb + sg * 16;
#pragma unroll
  for (int i = 0; i < 16; i += 4) {
    float4 f = *(const float4*)(ip + i);
    t[r][sg * 16 + i]     = f2b(f.x);
    t[r][sg * 16 + i + 1] = f2b(f.y);
    t[r][sg * 16 + i + 2] = f2b(f.z);
    t[r][sg * 16 + i + 3] = f2b(f.w);
  }
  __syncthreads();
  short8 v0, v1;
#pragma unroll
  for (int i = 0; i < 8; i++) v0[i] = (short)t[sg * 16 + i][r];
#pragma unroll
  for (int i = 0; i < 8; i++) v1[i] = (short)t[sg * 16 + 8 + i][r];
  *(short8*)(out + (long)(cb + r) * outRS + rb + sg * 16)     = v0;
  *(short8*)(out + (long)(cb + r) * outRS + rb + sg * 16 + 8) = v1;
}

__global__ __launch_bounds__(256) void prep(
    const float* __restrict__ x, u16* __restrict__ xb,
    const float* __restrict__ w_attn, u16* __restrict__ wTa,
    const float* __restrict__ w_proj, u16* __restrict__ wTp)
{
  const int bid = blockIdx.x, tid = threadIdx.x;
  if (bid < 6144) {
    int i = (bid * 256 + tid) * 4;
    float4 f = *(const float4*)(x + i);
    short4v v;
    v[0] = (short)f2b(f.x); v[1] = (short)f2b(f.y);
    v[2] = (short)f2b(f.z); v[3] = (short)f2b(f.w);
    *(short4v*)(xb + i) = v;
  } else if (bid < 6576) {
    int t = bid - 6144;                 // 36 x 12 tiles of w_attn [768][2304]
    tile_transpose_f2b(w_attn, wTa, 2304, 768, (t / 36) * 64, (t % 36) * 64, tid);
  } else {
    int t = bid - 6576;                 // 12 x 12 tiles of w_proj [768][768]
    tile_transpose_f2b(w_proj, wTp, 768, 768, (t / 12) * 64, (t % 12) * 64, tid);
  }
}

// ---------------------------------------------------------------------------
// Legacy C = A * Bt^T + bias (used for the proj GEMM, now 128x128 tiles).
// ---------------------------------------------------------------------------
__device__ __forceinline__ void store_out(u16* p, float v)  { *p = f2b(v); }
__device__ __forceinline__ void store_out(float* p, float v) { *p = v; }

template <int BM>
__device__ __forceinline__ void stage(
    const u16* __restrict__ A, const u16* __restrict__ Bt,
    long rowbase, long colbase, int K, int k0,
    u16* dA, u16* dB, int tid)
{
  const int c0 = tid, c1 = tid + 256;
  const int ar0 = c0 >> 2, ak0 = (c0 & 3) * 8;
  const int ar1 = c1 >> 2, ak1 = (c1 & 3) * 8;
  gld_lds16(A + (rowbase + ar0) * K + k0 + ak0, dA + c0 * 8);
  if (BM == 128)
    gld_lds16(A + (rowbase + ar1) * K + k0 + ak1, dA + c1 * 8);
  gld_lds16(Bt + (colbase + ar0) * K + k0 + ak0, dB + c0 * 8);
  gld_lds16(Bt + (colbase + ar1) * K + k0 + ak1, dB + c1 * 8);
}

template <typename OT, int BM, bool SPLIT>
__global__ __launch_bounds__(256) void gemm_bt_bias(
    const u16* __restrict__ A, const u16* __restrict__ Bt,
    const float* __restrict__ bias, OT* __restrict__ C, u16* __restrict__ vT,
    int M, int N, int K, int strideC)
{
  constexpr int WNF = (BM == 128) ? 4 : 2;      // n-frags per wave
  __shared__ __align__(16) u16 sA[2][BM * 32];
  __shared__ __align__(16) u16 sB[2][128 * 32];
  const int tid = threadIdx.x;
  const int lane = tid & 63;
  const int wave = tid >> 6;
  const int wm = (BM == 128) ? (wave >> 1) * 64 : 0;
  const int wn = (BM == 128) ? (wave & 1) * 64 : wave * 32;
  const int l15 = lane & 15;
  const int q = lane >> 4;
  const long rowbase = (long)blockIdx.y * BM;
  const long colbase = (long)blockIdx.x * 128;

  floatx4 acc[4][WNF];
#pragma unroll
  for (int i = 0; i < 4; i++)
#pragma unroll
    for (int j = 0; j < WNF; j++) acc[i][j] = (floatx4){0.f, 0.f, 0.f, 0.f};

  stage<BM>(A, Bt, rowbase, colbase, K, 0, sA[0], sB[0], tid);
  __syncthreads();   // buf0 ready

  const int NIT = K / 32;
  for (int it = 0; it < NIT; ++it) {
    const int cur = it & 1;
    if (it + 1 < NIT)
      stage<BM>(A, Bt, rowbase, colbase, K, (it + 1) * 32, sA[cur ^ 1], sB[cur ^ 1], tid);
    short8 af[4], bf[WNF];
#pragma unroll
    for (int mt = 0; mt < 4; mt++)
      af[mt] = *(const short8*)(sA[cur] + (wm + mt * 16 + l15) * 32 + q * 8);
#pragma unroll
    for (int nt = 0; nt < WNF; nt++)
      bf[nt] = *(const short8*)(sB[cur] + (wn + nt * 16 + l15) * 32 + q * 8);
#pragma unroll
    for (int mt = 0; mt < 4; mt++)
#pragma unroll
      for (int nt = 0; nt < WNF; nt++)
        acc[mt][nt] = __builtin_amdgcn_mfma_f32_16x16x32_bf16(af[mt], bf[nt], acc[mt][nt], 0, 0, 0);
    if (it + 1 < NIT) __syncthreads();
  }

  if (SPLIT && colbase >= 1536) {
    const long b = rowbase >> 10;
    const int t0b = (int)(rowbase & 1023) + wm;
#pragma unroll
    for (int nt = 0; nt < WNF; nt++) {
      const int col = (int)colbase + wn + nt * 16 + l15;
      const float bv = bias[col];
      const int dloc = col - 1536;
      u16* bp = vT + (b * 12 + (dloc >> 6)) * 65536L + (long)(dloc & 63) * 1024;
#pragma unroll
      for (int mt = 0; mt < 4; mt++) {
        short4v pv;
#pragma unroll
        for (int r = 0; r < 4; r++) pv[r] = (short)f2b(acc[mt][nt][r] + bv);
        *(short4v*)(bp + t0b + mt * 16 + q * 4) = pv;
      }
    }
  } else {
#pragma unroll
    for (int nt = 0; nt < WNF; nt++) {
      const long col = colbase + wn + nt * 16 + l15;
      const float bv = bias[col];
#pragma unroll
      for (int mt = 0; mt < 4; mt++)
#pragma unroll
        for (int r = 0; r < 4; r++) {
          const long row = rowbase + wm + mt * 16 + q * 4 + r;
          store_out(C + row * strideC + col, acc[mt][nt][r] + bv);
        }
    }
  }
}

// ---------------------------------------------------------------------------
// R9: qkv GEMM, deep-pipelined, SPILL-FREE geometry (m201 wave layout).
// Tile 256x256, BK=32, 4 LDS slots (128 KiB), 512 thr = 8 waves as 2M x 4N,
// per-wave 128x64 output -> acc[8][4] = 128 VGPRs (fits the 256 cap;
// R8's 4x9=144-frag layout spilled: VGPR=128 reported, WRITE +29MB scratch,
// 158us first-dispatch).  Grid 9x32 = 288 blocks (256 + 32-block tail).
//
// Schedule per K-tile j (slot j&3), distance-3 prefetch into slot (j+3)&3
// (= slot (j-1)&3, whose reads were consumed before the previous boundary
// barrier): phase A = {bf[4]+af[0..3] ds_reads, stage A-chunks, barrier,
// setprio(1) 16 MFMA}, phase B = {af[4..7] ds_reads, stage B-chunks,
// setprio(1) 16 MFMA}, boundary = counted s_waitcnt vmcnt(8) (never 0 until
// the 2-tile tail) + raw s_barrier. Uniform 4 loads/thread/tile so the
// vmcnt arithmetic is exact for every wave.
//
// LDS swizzle (T2, verified R8: SQ_LDS_BANK_CONFLICT = 0): element
// (row, k-octet o) lives at row*32 + ((o ^ ((row>>1)&3))<<3); inverse
// permutation applied to the GLOBAL source column (rule 21), LDS dest linear.
// ---------------------------------------------------------------------------
#define QKV_K 768
#define QKV_NT 24   // 768/32

__global__ __launch_bounds__(512, 2) void gemm_qkv_256(
    const u16* __restrict__ A, const u16* __restrict__ Bt,
    const float* __restrict__ bias, u16* __restrict__ qkOut, u16* __restrict__ vT)
{
  __shared__ __align__(16) u16 sA[4][256 * 32];   // 64 KiB
  __shared__ __align__(16) u16 sB[4][256 * 32];   // 64 KiB

  // XCD-aware bijective swizzle: 288 = 8 XCDs x 36; each XCD gets 4 full
  // row-panels (A reuse in its private L2).
  const int bid0 = blockIdx.x;
  const int wg = (bid0 & 7) * 36 + (bid0 >> 3);
  const int bx = wg % 9;              // col tile (0..8)
  const int by = wg / 9;              // row tile (0..31)

  const int tid = threadIdx.x;
  const int lane = tid & 63;
  const int l15 = lane & 15, q = lane >> 4;
  const int wave = tid >> 6;
  const int wm = (wave >> 2) * 128;   // 2 M-groups of waves
  const int wn = (wave & 3) * 64;     // 4 N-groups of waves
  const long rowbase = (long)by * 256;
  const long colbase = (long)bx * 256;
  // swizzled k-octet offset for frag reads (u16 units)
  const int xq = ((q ^ ((l15 >> 1) & 3)) << 3);

  // staging chunk c (16B): LDS row = c>>2, octet = c&3;
  // pre-swizzled global k-octet = (c&3) ^ ((c>>3)&3)
  const int ca0 = tid, ca1 = tid + 512;
  const u16* pa0 = A + (rowbase + (ca0 >> 2)) * QKV_K + ((((ca0 & 3) ^ ((ca0 >> 3) & 3))) << 3);
  const u16* pa1 = A + (rowbase + (ca1 >> 2)) * QKV_K + ((((ca1 & 3) ^ ((ca1 >> 3) & 3))) << 3);
  const u16* pb0 = Bt + (colbase + (ca0 >> 2)) * QKV_K + ((((ca0 & 3) ^ ((ca0 >> 3) & 3))) << 3);
  const u16* pb1 = Bt + (colbase + (ca1 >> 2)) * QKV_K + ((((ca1 & 3) ^ ((ca1 >> 3) & 3))) << 3);

#define STAGE_A(t, s) do { \
    gld_lds16(pa0 + (long)(t) * 32, &sA[s][ca0 * 8]); \
    gld_lds16(pa1 + (long)(t) * 32, &sA[s][ca1 * 8]); } while (0)
#define STAGE_B(t, s) do { \
    gld_lds16(pb0 + (long)(t) * 32, &sB[s][ca0 * 8]); \
    gld_lds16(pb1 + (long)(t) * 32, &sB[s][ca1 * 8]); } while (0)

  floatx4 acc[8][4];
#pragma unroll
  for (int i = 0; i < 8; i++)
#pragma unroll
    for (int n = 0; n < 4; n++) acc[i][n] = (floatx4){0.f, 0.f, 0.f, 0.f};

  // prologue: tiles 0,1,2 -> slots 0,1,2 (12 loads/thread; oldest 4 = tile 0)
  STAGE_A(0, 0); STAGE_B(0, 0);
  STAGE_A(1, 1); STAGE_B(1, 1);
  STAGE_A(2, 2); STAGE_B(2, 2);
  asm volatile("s_waitcnt vmcnt(8)" ::: "memory");  // own tile-0 loads landed
  __builtin_amdgcn_s_barrier();                     // => all waves' tile-0 done

#pragma unroll 4
  for (int j = 0; j < QKV_NT; ++j) {
    const int slot = j & 3;
    const u16* ap = sA[slot];
    const u16* bp = sB[slot];

    // ---- phase A: 8 ds_reads, stage A of j+3, 16 MFMA ----
    short8 bf[4];
#pragma unroll
    for (int nt = 0; nt < 4; nt++)
      bf[nt] = *(const short8*)(bp + (wn + nt * 16 + l15) * 32 + xq);
    short8 af[4];
#pragma unroll
    for (int mt = 0; mt < 4; mt++)
      af[mt] = *(const short8*)(ap + (wm + mt * 16 + l15) * 32 + xq);
    if (j + 3 < QKV_NT) STAGE_A(j + 3, (j + 3) & 3);
    __builtin_amdgcn_s_barrier();   // phase alignment across waves
    __builtin_amdgcn_s_setprio(1);
#pragma unroll
    for (int mt = 0; mt < 4; mt++)
#pragma unroll
      for (int nt = 0; nt < 4; nt++)
        acc[mt][nt] = __builtin_amdgcn_mfma_f32_16x16x32_bf16(af[mt], bf[nt], acc[mt][nt], 0, 0, 0);
    __builtin_amdgcn_s_setprio(0);

    // ---- phase B: 4 ds_reads, stage B of j+3, 16 MFMA ----
#pragma unroll
    for (int mt = 0; mt < 4; mt++)
      af[mt] = *(const short8*)(ap + (wm + 64 + mt * 16 + l15) * 32 + xq);
    if (j + 3 < QKV_NT) STAGE_B(j + 3, (j + 3) & 3);
    __builtin_amdgcn_s_setprio(1);
#pragma unroll
    for (int mt = 0; mt < 4; mt++)
#pragma unroll
      for (int nt = 0; nt < 4; nt++)
        acc[4 + mt][nt] = __builtin_amdgcn_mfma_f32_16x16x32_bf16(af[mt], bf[nt], acc[4 + mt][nt], 0, 0, 0);
    __builtin_amdgcn_s_setprio(0);

    // ---- boundary: tile j+1 must be resident; never drain to 0 mid-loop ----
    if (j < QKV_NT - 1) {
      if (j + 3 < QKV_NT)      asm volatile("s_waitcnt vmcnt(8)" ::: "memory");
      else if (j + 2 < QKV_NT) asm volatile("s_waitcnt vmcnt(4)" ::: "memory");
      else                     asm volatile("s_waitcnt vmcnt(0)" ::: "memory");
      __builtin_amdgcn_s_barrier();
    }
  }
#undef STAGE_A
#undef STAGE_B

  // ---- epilogue: col tiles 0..5 -> qk[row][1536]; tiles 6..8 (V) -> vT ----
  if (colbase >= 1536) {
    const long bb = rowbase >> 10;
    const int t0 = (int)(rowbase & 1023) + wm;
#pragma unroll
    for (int nt = 0; nt < 4; nt++) {
      const int col = (int)colbase + wn + nt * 16 + l15;
      const float bv = bias[col];
      const int dloc = col - 1536;
      u16* op = vT + (bb * 12 + (dloc >> 6)) * 65536L + (long)(dloc & 63) * 1024;
#pragma unroll
      for (int mt = 0; mt < 8; mt++) {
        short4v pv;
#pragma unroll
        for (int r = 0; r < 4; r++) pv[r] = (short)f2b(acc[mt][nt][r] + bv);
        *(short4v*)(op + t0 + mt * 16 + q * 4) = pv;
      }
    }
  } else {
#pragma unroll
    for (int nt = 0; nt < 4; nt++) {
      const long col = colbase + wn + nt * 16 + l15;
      const float bv = bias[col];
#pragma unroll
      for (int mt = 0; mt < 8; mt++)
#pragma unroll
        for (int r = 0; r < 4; r++) {
          const long row = rowbase + wm + mt * 16 + q * 4 + r;
          qkOut[row * 1536 + col] = f2b(acc[mt][nt][r] + bv);
        }
    }
  }
}

// ---------------------------------------------------------------------------
// Flash attention, causal. One block = (b*12+h, q-tile of 64 rows), 256 thr.
// (unchanged from R5/R7 best)
// ---------------------------------------------------------------------------
__global__ __launch_bounds__(256) void attn_fwd(
    const u16* __restrict__ qk, const u16* __restrict__ vT, u16* __restrict__ y)
{
  const int bh = blockIdx.x;        // b*12 + h
  const int qt = 15 - blockIdx.y;   // reversed: long blocks dispatch first
  const int b = bh / 12, h = bh % 12;
  const long rowOff = (long)b * 1024;
  const int qb = qt * 64;

  __shared__ __align__(16) u16 sK[64 * 72];
  __shared__ __align__(16) u16 sV[2][64 * 72];  // V^T [d][key], double-buffered
  __shared__ __align__(16) u16 sP[64 * 72];     // P [qrow][key]

  const int tid = threadIdx.x;
  const int lane = tid & 63, wave = tid >> 6;
  const int l15 = lane & 15, q = lane >> 4;
  const int qrow_g = qb + wave * 16 + l15;    // this lane's softmax row

  short8 qf[2];
  {
    const u16* qp = qk + (long)(rowOff + qrow_g) * 1536 + h * 64 + q * 8;
    short8 a0 = *(const short8*)(qp);
    short8 a1 = *(const short8*)(qp + 32);
#pragma unroll
    for (int i = 0; i < 8; i++) {
      a0[i] = (short)f2b(b2f((u16)a0[i]) * 0.125f);
      a1[i] = (short)f2b(b2f((u16)a1[i]) * 0.125f);
    }
    qf[0] = a0; qf[1] = a1;
  }

  float m_i = -1e30f, l_i = 0.f;
  floatx4 o[4];
#pragma unroll
  for (int nt = 0; nt < 4; nt++) o[nt] = (floatx4){0.f, 0.f, 0.f, 0.f};

  for (int j = 0; j <= qt; j++) {
    const int jb = j * 64;
    u16* sVc = sV[j & 1];
#pragma unroll
    for (int rep = 0; rep < 2; rep++) {
      int idx = tid + rep * 256;
      int r = idx >> 3, ch = (idx & 7) * 8;
      *(short8*)(sK + r * 72 + ch) =
          *(const short8*)(qk + (long)(rowOff + jb + r) * 1536 + 768 + h * 64 + ch);
      *(short8*)(sVc + r * 72 + ch) =
          *(const short8*)(vT + (long)bh * 65536 + (long)r * 1024 + jb + ch);
    }
    __syncthreads();

    floatx4 sf[4];
#pragma unroll
    for (int mt = 0; mt < 4; mt++) sf[mt] = (floatx4){0.f, 0.f, 0.f, 0.f};
#pragma unroll
    for (int kk = 0; kk < 2; kk++) {
#pragma unroll
      for (int mt = 0; mt < 4; mt++) {
        short8 kf = *(const short8*)(sK + (mt * 16 + l15) * 72 + kk * 32 + q * 8);
        sf[mt] = __builtin_amdgcn_mfma_f32_16x16x32_bf16(kf, qf[kk], sf[mt], 0, 0, 0);
      }
    }

    float mx = m_i;
#pragma unroll
    for (int mt = 0; mt < 4; mt++)
#pragma unroll
      for (int r = 0; r < 4; r++) {
        int key_g = jb + mt * 16 + q * 4 + r;
        float v = sf[mt][r];
        if (key_g > qrow_g) v = -1e30f;
        sf[mt][r] = v;
        mx = fmaxf(mx, v);
      }
    mx = fmaxf(mx, __shfl_xor(mx, 16));
    mx = fmaxf(mx, __shfl_xor(mx, 32));
    float al = __expf(m_i - mx);
    m_i = mx;
    float rsum = 0.f;
#pragma unroll
    for (int mt = 0; mt < 4; mt++) {
      short4v pv;
#pragma unroll
      for (int r = 0; r < 4; r++) {
        float p = __expf(sf[mt][r] - mx);
        rsum += p;
        pv[r] = (short)f2b(p);
      }
      *(short4v*)(sP + (wave * 16 + l15) * 72 + mt * 16 + q * 4) = pv;
    }
    rsum += __shfl_xor(rsum, 16);
    rsum += __shfl_xor(rsum, 32);
    l_i = l_i * al + rsum;
    __syncthreads();   // sP (+ this iter's sV) visible before PV

    float al_r[4];
#pragma unroll
    for (int r = 0; r < 4; r++) al_r[r] = __shfl(al, q * 4 + r);
#pragma unroll
    for (int nt = 0; nt < 4; nt++)
#pragma unroll
      for (int r = 0; r < 4; r++) o[nt][r] *= al_r[r];
#pragma unroll
    for (int kk = 0; kk < 2; kk++) {
      short8 pf = *(const short8*)(sP + (wave * 16 + l15) * 72 + kk * 32 + q * 8);
#pragma unroll
      for (int nt = 0; nt < 4; nt++) {
        short8 vf = *(const short8*)(sVc + (nt * 16 + l15) * 72 + kk * 32 + q * 8);
        o[nt] = __builtin_amdgcn_mfma_f32_16x16x32_bf16(pf, vf, o[nt], 0, 0, 0);
      }
    }
  }

  float linv = 1.f / l_i;
  float li_r[4];
#pragma unroll
  for (int r = 0; r < 4; r++) li_r[r] = __shfl(linv, q * 4 + r);
#pragma unroll
  for (int nt = 0; nt < 4; nt++)
#pragma unroll
    for (int r = 0; r < 4; r++) {
      int row = qb + wave * 16 + q * 4 + r;
      int col = h * 64 + nt * 16 + l15;
      y[(rowOff + row) * 768 + col] = f2b(o[nt][r] * li_r[r]);
    }
}

// ---------------------------------------------------------------------------
extern "C" void kernel_launch(void* const* d_in, const int* in_sizes, int n_in,
                              void* d_out, int out_size, void* d_ws, size_t ws_size,
                              hipStream_t stream) {
  const float* x      = (const float*)d_in[0];  // [8192][768] fp32
  const float* w_attn = (const float*)d_in[1];  // [768][2304] fp32
  const float* b_attn = (const float*)d_in[2];  // [2304] fp32
  const float* w_proj = (const float*)d_in[3];  // [768][768] fp32
  const float* b_proj = (const float*)d_in[4];  // [768] fp32
  float* out = (float*)d_out;                   // [8192][768] fp32

  char* ws = (char*)d_ws;
  u16* xb   = (u16*)ws; ws += (size_t)8192 * 768 * 2;     // 12.6 MB
  u16* wTa  = (u16*)ws; ws += (size_t)2304 * 768 * 2;     //  3.5 MB
  u16* wTp  = (u16*)ws; ws += (size_t)768 * 768 * 2;      //  1.2 MB
  u16* qk   = (u16*)ws; ws += (size_t)8192 * 1536 * 2;    // 25.2 MB (Q|K)
  u16* vT   = (u16*)ws; ws += (size_t)96 * 64 * 1024 * 2; // 12.6 MB (V^T)
  u16* yatt = (u16*)ws; ws += (size_t)8192 * 768 * 2;     // 12.6 MB

  // fused prep: x->bf16 + both weight transposes
  prep<<<dim3(6720), 256, 0, stream>>>(x, xb, w_attn, wTa, w_proj, wTp);

  // qkv GEMM: 256x256 tiles, grid 288 (XCD-swizzled inside the kernel)
  gemm_qkv_256<<<dim3(288), 512, 0, stream>>>(xb, wTa, b_attn, qk, vT);

  // flash attention (V pre-transposed; in-register softmax)
  attn_fwd<<<dim3(96, 16), 256, 0, stream>>>(qk, vT, yatt);

  // out = yatt @ w_proj + b_proj   (fp32 out, 128x128 tiles)
  gemm_bt_bias<float, 128, false><<<dim3(6, 64), 256, 0, stream>>>(
      yatt, wTp, b_proj, out, (u16*)nullptr, 8192, 768, 768, 768);
}

// Round 3
// 196.700 us; speedup vs baseline: 1.0977x; 1.0568x over previous
//
#include <hip/hip_runtime.h>
#include <hip/hip_bf16.h>
#include <stdint.h>

typedef unsigned short u16;
typedef short short8 __attribute__((ext_vector_type(8)));
typedef short short4v __attribute__((ext_vector_type(4)));
typedef float floatx4 __attribute__((ext_vector_type(4)));

__device__ __forceinline__ float b2f(u16 v) {
  union { unsigned int u; float f; } c; c.u = ((unsigned int)v) << 16; return c.f;
}
__device__ __forceinline__ u16 f2b(float f) {
  union { float f; unsigned int u; } c; c.f = f;
  unsigned int u = c.u;
  return (u16)((u + 0x7fffu + ((u >> 16) & 1u)) >> 16);  // RNE
}

// async global->LDS, 16B per lane. LDS dest must be wave-uniform base + lane*16.
__device__ __forceinline__ void gld_lds16(const u16* g, u16* l) {
  __builtin_amdgcn_global_load_lds(
      (const __attribute__((address_space(1))) unsigned int*)g,
      (__attribute__((address_space(3))) unsigned int*)l,
      16, 0, 0);
}

// ---------------------------------------------------------------------------
// Fused prep: x fp32->bf16 (blocks 0..6143), w_attn T (6144..6575),
// w_proj T (6576..6719). Transposes also convert fp32->bf16.
// ---------------------------------------------------------------------------
__device__ __forceinline__ void tile_transpose_f2b(
    const float* __restrict__ in, u16* __restrict__ out,
    int inRS, int outRS, int rb, int cb, int tid)
{
  __shared__ __align__(16) u16 t[64][72];
  const int r = tid >> 2, sg = tid & 3;
  const float* ip = in + (long)(rb + r) * inRS + cb + sg * 16;
#pragma unroll
  for (int i = 0; i < 16; i += 4) {
    float4 f = *(const float4*)(ip + i);
    t[r][sg * 16 + i]     = f2b(f.x);
    t[r][sg * 16 + i + 1] = f2b(f.y);
    t[r][sg * 16 + i + 2] = f2b(f.z);
    t[r][sg * 16 + i + 3] = f2b(f.w);
  }
  __syncthreads();
  short8 v0, v1;
#pragma unroll
  for (int i = 0; i < 8; i++) v0[i] = (short)t[sg * 16 + i][r];
#pragma unroll
  for (int i = 0; i < 8; i++) v1[i] = (short)t[sg * 16 + 8 + i][r];
  *(short8*)(out + (long)(cb + r) * outRS + rb + sg * 16)     = v0;
  *(short8*)(out + (long)(cb + r) * outRS + rb + sg * 16 + 8) = v1;
}

__global__ __launch_bounds__(256) void prep(
    const float* __restrict__ x, u16* __restrict__ xb,
    const float* __restrict__ w_attn, u16* __restrict__ wTa,
    const float* __restrict__ w_proj, u16* __restrict__ wTp)
{
  const int bid = blockIdx.x, tid = threadIdx.x;
  if (bid < 6144) {
    int i = (bid * 256 + tid) * 4;
    float4 f = *(const float4*)(x + i);
    short4v v;
    v[0] = (short)f2b(f.x); v[1] = (short)f2b(f.y);
    v[2] = (short)f2b(f.z); v[3] = (short)f2b(f.w);
    *(short4v*)(xb + i) = v;
  } else if (bid < 6576) {
    int t = bid - 6144;                 // 36 x 12 tiles of w_attn [768][2304]
    tile_transpose_f2b(w_attn, wTa, 2304, 768, (t / 36) * 64, (t % 36) * 64, tid);
  } else {
    int t = bid - 6576;                 // 12 x 12 tiles of w_proj [768][768]
    tile_transpose_f2b(w_proj, wTp, 768, 768, (t / 12) * 64, (t % 12) * 64, tid);
  }
}

// ---------------------------------------------------------------------------
// Legacy C = A * Bt^T + bias (used for the proj GEMM, 128x128 tiles).
// ---------------------------------------------------------------------------
__device__ __forceinline__ void store_out(u16* p, float v)  { *p = f2b(v); }
__device__ __forceinline__ void store_out(float* p, float v) { *p = v; }

template <int BM>
__device__ __forceinline__ void stage(
    const u16* __restrict__ A, const u16* __restrict__ Bt,
    long rowbase, long colbase, int K, int k0,
    u16* dA, u16* dB, int tid)
{
  const int c0 = tid, c1 = tid + 256;
  const int ar0 = c0 >> 2, ak0 = (c0 & 3) * 8;
  const int ar1 = c1 >> 2, ak1 = (c1 & 3) * 8;
  gld_lds16(A + (rowbase + ar0) * K + k0 + ak0, dA + c0 * 8);
  if (BM == 128)
    gld_lds16(A + (rowbase + ar1) * K + k0 + ak1, dA + c1 * 8);
  gld_lds16(Bt + (colbase + ar0) * K + k0 + ak0, dB + c0 * 8);
  gld_lds16(Bt + (colbase + ar1) * K + k0 + ak1, dB + c1 * 8);
}

template <typename OT, int BM, bool SPLIT>
__global__ __launch_bounds__(256) void gemm_bt_bias(
    const u16* __restrict__ A, const u16* __restrict__ Bt,
    const float* __restrict__ bias, OT* __restrict__ C, u16* __restrict__ vT,
    int M, int N, int K, int strideC)
{
  constexpr int WNF = (BM == 128) ? 4 : 2;      // n-frags per wave
  __shared__ __align__(16) u16 sA[2][BM * 32];
  __shared__ __align__(16) u16 sB[2][128 * 32];
  const int tid = threadIdx.x;
  const int lane = tid & 63;
  const int wave = tid >> 6;
  const int wm = (BM == 128) ? (wave >> 1) * 64 : 0;
  const int wn = (BM == 128) ? (wave & 1) * 64 : wave * 32;
  const int l15 = lane & 15;
  const int q = lane >> 4;
  const long rowbase = (long)blockIdx.y * BM;
  const long colbase = (long)blockIdx.x * 128;

  floatx4 acc[4][WNF];
#pragma unroll
  for (int i = 0; i < 4; i++)
#pragma unroll
    for (int j = 0; j < WNF; j++) acc[i][j] = (floatx4){0.f, 0.f, 0.f, 0.f};

  stage<BM>(A, Bt, rowbase, colbase, K, 0, sA[0], sB[0], tid);
  __syncthreads();   // buf0 ready

  const int NIT = K / 32;
  for (int it = 0; it < NIT; ++it) {
    const int cur = it & 1;
    if (it + 1 < NIT)
      stage<BM>(A, Bt, rowbase, colbase, K, (it + 1) * 32, sA[cur ^ 1], sB[cur ^ 1], tid);
    short8 af[4], bf[WNF];
#pragma unroll
    for (int mt = 0; mt < 4; mt++)
      af[mt] = *(const short8*)(sA[cur] + (wm + mt * 16 + l15) * 32 + q * 8);
#pragma unroll
    for (int nt = 0; nt < WNF; nt++)
      bf[nt] = *(const short8*)(sB[cur] + (wn + nt * 16 + l15) * 32 + q * 8);
#pragma unroll
    for (int mt = 0; mt < 4; mt++)
#pragma unroll
      for (int nt = 0; nt < WNF; nt++)
        acc[mt][nt] = __builtin_amdgcn_mfma_f32_16x16x32_bf16(af[mt], bf[nt], acc[mt][nt], 0, 0, 0);
    if (it + 1 < NIT) __syncthreads();
  }

  if (SPLIT && colbase >= 1536) {
    const long b = rowbase >> 10;
    const int t0b = (int)(rowbase & 1023) + wm;
#pragma unroll
    for (int nt = 0; nt < WNF; nt++) {
      const int col = (int)colbase + wn + nt * 16 + l15;
      const float bv = bias[col];
      const int dloc = col - 1536;
      u16* bp = vT + (b * 12 + (dloc >> 6)) * 65536L + (long)(dloc & 63) * 1024;
#pragma unroll
      for (int mt = 0; mt < 4; mt++) {
        short4v pv;
#pragma unroll
        for (int r = 0; r < 4; r++) pv[r] = (short)f2b(acc[mt][nt][r] + bv);
        *(short4v*)(bp + t0b + mt * 16 + q * 4) = pv;
      }
    }
  } else {
#pragma unroll
    for (int nt = 0; nt < WNF; nt++) {
      const long col = colbase + wn + nt * 16 + l15;
      const float bv = bias[col];
#pragma unroll
      for (int mt = 0; mt < 4; mt++)
#pragma unroll
        for (int r = 0; r < 4; r++) {
          const long row = rowbase + wm + mt * 16 + q * 4 + r;
          store_out(C + row * strideC + col, acc[mt][nt][r] + bv);
        }
    }
  }
}

// ---------------------------------------------------------------------------
// R10: qkv GEMM, zero-tail grid + higher TLP.
// Tile 256x288, BK=32, 4 LDS slots (136 KiB), 768 thr = 12 waves (2M x 6N),
// per-wave 128x48 -> acc[8][3] = 96 acc regs (safe under the 3-waves/SIMD
// budget; R8's spill was 144).  Grid 32x8 = 256 blocks = exactly 1/CU,
// NO second scheduling round (R9: 288 blocks -> 2 rounds, round 2 at 12.5%
// chip utilization -> Occupancy 11.4%, dur 2x per-block time).
//
// Pipeline (verified R8/R9): distance-3 prefetch into slot (j+3)&3, counted
// per-wave vmcnt (staging is wave-uniform: waves 0-3 carry 4 loads/tile,
// waves 4-5 carry 3, waves 6-11 carry 2 -> steady-state wait vmcnt(2L)),
// setprio(1) around MFMA clusters, 2 barriers/tile.
//
// LDS swizzle (T2, measured 0 conflicts in R8/R9): element (row, octet o)
// at row*32 + ((o ^ ((row>>1)&3))<<3); inverse permutation applied to the
// GLOBAL source column (rule 21), LDS dest stays linear for global_load_lds.
// XCD swizzle: 256 = 8 XCDs x 32; each XCD gets 4 row-panels x all 8
// col-tiles (kept R9's FETCH = 27.8 MB, near-ideal).
// ---------------------------------------------------------------------------
#define QKV_K 768
#define QKV_NT 24   // 768/32
#define VMW(n) asm volatile("s_waitcnt vmcnt(" #n ")" ::: "memory")

__global__ __launch_bounds__(768, 3) void gemm_qkv_288(
    const u16* __restrict__ A, const u16* __restrict__ Bt,
    const float* __restrict__ bias, u16* __restrict__ qkOut, u16* __restrict__ vT)
{
  __shared__ __align__(16) u16 sA[4][256 * 32];   // 64 KiB
  __shared__ __align__(16) u16 sB[4][288 * 32];   // 72 KiB

  const int bid = blockIdx.x;
  const int wg = (bid & 7) * 32 + (bid >> 3);
  const int bx = wg & 7;        // col tile 0..7 (288 cols each)
  const int by = wg >> 3;       // row tile 0..31 (256 rows each)

  const int tid = threadIdx.x;
  const int lane = tid & 63;
  const int l15 = lane & 15, q = lane >> 4;
  const int wave = tid >> 6;          // 0..11
  const int wm = (wave / 6) * 128;    // 2 M-groups
  const int wn = (wave % 6) * 48;     // 6 N-groups (3 frags each)
  const long rowbase = (long)by * 256;
  const long colbase = (long)bx * 288;
  // swizzled k-octet offset for frag reads (u16 units)
  const int xq = ((q ^ ((l15 >> 1) & 3)) << 3);

  // staging chunk c (16B): LDS row = c>>2, octet = c&3;
  // pre-swizzled global k-octet = (c&3) ^ ((c>>3)&3)
  const int cA0 = tid, cA1 = 768 + tid;   // A: 1024 chunks (waves 0-3 take 2nd)
  const int cB0 = tid, cB1 = 768 + tid;   // B: 1152 chunks (waves 0-5 take 2nd)
  const u16* pa0 = A + (rowbase + (cA0 >> 2)) * QKV_K + ((((cA0 & 3) ^ ((cA0 >> 3) & 3))) << 3);
  const u16* pa1 = A + (rowbase + (cA1 >> 2)) * QKV_K + ((((cA1 & 3) ^ ((cA1 >> 3) & 3))) << 3);
  const u16* pb0 = Bt + (colbase + (cB0 >> 2)) * QKV_K + ((((cB0 & 3) ^ ((cB0 >> 3) & 3))) << 3);
  const u16* pb1 = Bt + (colbase + (cB1 >> 2)) * QKV_K + ((((cB1 & 3) ^ ((cB1 >> 3) & 3))) << 3);
  const bool hasA1 = (tid < 256);   // wave-uniform
  const bool hasB1 = (tid < 384);   // wave-uniform

#define STAGE(t, s) do { \
    const long k0_ = (long)(t) * 32; \
    gld_lds16(pa0 + k0_, &sA[s][cA0 * 8]); \
    if (hasA1) gld_lds16(pa1 + k0_, &sA[s][cA1 * 8]); \
    gld_lds16(pb0 + k0_, &sB[s][cB0 * 8]); \
    if (hasB1) gld_lds16(pb1 + k0_, &sB[s][cB1 * 8]); } while (0)

  floatx4 acc[8][3];
#pragma unroll
  for (int i = 0; i < 8; i++)
#pragma unroll
    for (int n = 0; n < 3; n++) acc[i][n] = (floatx4){0.f, 0.f, 0.f, 0.f};

  // prologue: tiles 0,1,2 -> slots 0,1,2; wait for own tile-0 loads
  STAGE(0, 0); STAGE(1, 1); STAGE(2, 2);
  if (wave < 4) VMW(8); else if (wave < 6) VMW(6); else VMW(4);
  __builtin_amdgcn_s_barrier();   // all waves' tile-0 resident

#pragma unroll 4
  for (int j = 0; j < QKV_NT; ++j) {
    const int slot = j & 3;
    const u16* ap = sA[slot];
    const u16* bp = sB[slot];

    // ---- phase A: 7 ds_reads, stage tile j+3, 12 MFMA ----
    short8 bf[3];
#pragma unroll
    for (int nt = 0; nt < 3; nt++)
      bf[nt] = *(const short8*)(bp + (wn + nt * 16 + l15) * 32 + xq);
    short8 af[4];
#pragma unroll
    for (int mt = 0; mt < 4; mt++)
      af[mt] = *(const short8*)(ap + (wm + mt * 16 + l15) * 32 + xq);
    if (j + 3 < QKV_NT) STAGE(j + 3, (j + 3) & 3);
    __builtin_amdgcn_s_barrier();   // phase alignment
    __builtin_amdgcn_s_setprio(1);
#pragma unroll
    for (int mt = 0; mt < 4; mt++)
#pragma unroll
      for (int nt = 0; nt < 3; nt++)
        acc[mt][nt] = __builtin_amdgcn_mfma_f32_16x16x32_bf16(af[mt], bf[nt], acc[mt][nt], 0, 0, 0);
    __builtin_amdgcn_s_setprio(0);

    // ---- phase B: 4 ds_reads, 12 MFMA ----
#pragma unroll
    for (int mt = 0; mt < 4; mt++)
      af[mt] = *(const short8*)(ap + (wm + 64 + mt * 16 + l15) * 32 + xq);
    __builtin_amdgcn_s_setprio(1);
#pragma unroll
    for (int mt = 0; mt < 4; mt++)
#pragma unroll
      for (int nt = 0; nt < 3; nt++)
        acc[4 + mt][nt] = __builtin_amdgcn_mfma_f32_16x16x32_bf16(af[mt], bf[nt], acc[4 + mt][nt], 0, 0, 0);
    __builtin_amdgcn_s_setprio(0);

    // ---- boundary: tile j+1 must be resident; counted waits, wave-uniform ----
    if (j < QKV_NT - 1) {
      if (j + 3 < QKV_NT) {        // 2 tiles outstanding after wait
        if (wave < 4) VMW(8); else if (wave < 6) VMW(6); else VMW(4);
      } else if (j + 2 < QKV_NT) { // 1 tile outstanding after wait
        if (wave < 4) VMW(4); else if (wave < 6) VMW(3); else VMW(2);
      } else {
        VMW(0);                    // 2-tile tail: full drain ok
      }
      __builtin_amdgcn_s_barrier();
    }
  }
#undef STAGE

  // ---- epilogue: per-fragment split at col 1536 (16-aligned inside bx=5) ----
#pragma unroll
  for (int nt = 0; nt < 3; nt++) {
    const int fragc = (int)colbase + wn + nt * 16;   // lane-invariant, 16-aligned
    const int col = fragc + l15;
    const float bv = bias[col];
    if (fragc >= 1536) {
      const long bb = rowbase >> 10;
      const int dloc = col - 1536;
      u16* op = vT + (bb * 12 + (dloc >> 6)) * 65536L + (long)(dloc & 63) * 1024;
      const int t0 = (int)(rowbase & 1023) + wm;
#pragma unroll
      for (int mt = 0; mt < 8; mt++) {
        short4v pv;
#pragma unroll
        for (int r = 0; r < 4; r++) pv[r] = (short)f2b(acc[mt][nt][r] + bv);
        *(short4v*)(op + t0 + mt * 16 + q * 4) = pv;
      }
    } else {
#pragma unroll
      for (int mt = 0; mt < 8; mt++)
#pragma unroll
        for (int r = 0; r < 4; r++) {
          const long row = rowbase + wm + mt * 16 + q * 4 + r;
          qkOut[row * 1536 + col] = f2b(acc[mt][nt][r] + bv);
        }
    }
  }
}
#undef VMW

// ---------------------------------------------------------------------------
// Flash attention, causal. One block = (b*12+h, q-tile of 64 rows), 256 thr.
// (unchanged from R5/R7 best)
// ---------------------------------------------------------------------------
__global__ __launch_bounds__(256) void attn_fwd(
    const u16* __restrict__ qk, const u16* __restrict__ vT, u16* __restrict__ y)
{
  const int bh = blockIdx.x;        // b*12 + h
  const int qt = 15 - blockIdx.y;   // reversed: long blocks dispatch first
  const int b = bh / 12, h = bh % 12;
  const long rowOff = (long)b * 1024;
  const int qb = qt * 64;

  __shared__ __align__(16) u16 sK[64 * 72];
  __shared__ __align__(16) u16 sV[2][64 * 72];  // V^T [d][key], double-buffered
  __shared__ __align__(16) u16 sP[64 * 72];     // P [qrow][key]

  const int tid = threadIdx.x;
  const int lane = tid & 63, wave = tid >> 6;
  const int l15 = lane & 15, q = lane >> 4;
  const int qrow_g = qb + wave * 16 + l15;    // this lane's softmax row

  short8 qf[2];
  {
    const u16* qp = qk + (long)(rowOff + qrow_g) * 1536 + h * 64 + q * 8;
    short8 a0 = *(const short8*)(qp);
    short8 a1 = *(const short8*)(qp + 32);
#pragma unroll
    for (int i = 0; i < 8; i++) {
      a0[i] = (short)f2b(b2f((u16)a0[i]) * 0.125f);
      a1[i] = (short)f2b(b2f((u16)a1[i]) * 0.125f);
    }
    qf[0] = a0; qf[1] = a1;
  }

  float m_i = -1e30f, l_i = 0.f;
  floatx4 o[4];
#pragma unroll
  for (int nt = 0; nt < 4; nt++) o[nt] = (floatx4){0.f, 0.f, 0.f, 0.f};

  for (int j = 0; j <= qt; j++) {
    const int jb = j * 64;
    u16* sVc = sV[j & 1];
#pragma unroll
    for (int rep = 0; rep < 2; rep++) {
      int idx = tid + rep * 256;
      int r = idx >> 3, ch = (idx & 7) * 8;
      *(short8*)(sK + r * 72 + ch) =
          *(const short8*)(qk + (long)(rowOff + jb + r) * 1536 + 768 + h * 64 + ch);
      *(short8*)(sVc + r * 72 + ch) =
          *(const short8*)(vT + (long)bh * 65536 + (long)r * 1024 + jb + ch);
    }
    __syncthreads();

    floatx4 sf[4];
#pragma unroll
    for (int mt = 0; mt < 4; mt++) sf[mt] = (floatx4){0.f, 0.f, 0.f, 0.f};
#pragma unroll
    for (int kk = 0; kk < 2; kk++) {
#pragma unroll
      for (int mt = 0; mt < 4; mt++) {
        short8 kf = *(const short8*)(sK + (mt * 16 + l15) * 72 + kk * 32 + q * 8);
        sf[mt] = __builtin_amdgcn_mfma_f32_16x16x32_bf16(kf, qf[kk], sf[mt], 0, 0, 0);
      }
    }

    float mx = m_i;
#pragma unroll
    for (int mt = 0; mt < 4; mt++)
#pragma unroll
      for (int r = 0; r < 4; r++) {
        int key_g = jb + mt * 16 + q * 4 + r;
        float v = sf[mt][r];
        if (key_g > qrow_g) v = -1e30f;
        sf[mt][r] = v;
        mx = fmaxf(mx, v);
      }
    mx = fmaxf(mx, __shfl_xor(mx, 16));
    mx = fmaxf(mx, __shfl_xor(mx, 32));
    float al = __expf(m_i - mx);
    m_i = mx;
    float rsum = 0.f;
#pragma unroll
    for (int mt = 0; mt < 4; mt++) {
      short4v pv;
#pragma unroll
      for (int r = 0; r < 4; r++) {
        float p = __expf(sf[mt][r] - mx);
        rsum += p;
        pv[r] = (short)f2b(p);
      }
      *(short4v*)(sP + (wave * 16 + l15) * 72 + mt * 16 + q * 4) = pv;
    }
    rsum += __shfl_xor(rsum, 16);
    rsum += __shfl_xor(rsum, 32);
    l_i = l_i * al + rsum;
    __syncthreads();   // sP (+ this iter's sV) visible before PV

    float al_r[4];
#pragma unroll
    for (int r = 0; r < 4; r++) al_r[r] = __shfl(al, q * 4 + r);
#pragma unroll
    for (int nt = 0; nt < 4; nt++)
#pragma unroll
      for (int r = 0; r < 4; r++) o[nt][r] *= al_r[r];
#pragma unroll
    for (int kk = 0; kk < 2; kk++) {
      short8 pf = *(const short8*)(sP + (wave * 16 + l15) * 72 + kk * 32 + q * 8);
#pragma unroll
      for (int nt = 0; nt < 4; nt++) {
        short8 vf = *(const short8*)(sVc + (nt * 16 + l15) * 72 + kk * 32 + q * 8);
        o[nt] = __builtin_amdgcn_mfma_f32_16x16x32_bf16(pf, vf, o[nt], 0, 0, 0);
      }
    }
  }

  float linv = 1.f / l_i;
  float li_r[4];
#pragma unroll
  for (int r = 0; r < 4; r++) li_r[r] = __shfl(linv, q * 4 + r);
#pragma unroll
  for (int nt = 0; nt < 4; nt++)
#pragma unroll
    for (int r = 0; r < 4; r++) {
      int row = qb + wave * 16 + q * 4 + r;
      int col = h * 64 + nt * 16 + l15;
      y[(rowOff + row) * 768 + col] = f2b(o[nt][r] * li_r[r]);
    }
}

// ---------------------------------------------------------------------------
extern "C" void kernel_launch(void* const* d_in, const int* in_sizes, int n_in,
                              void* d_out, int out_size, void* d_ws, size_t ws_size,
                              hipStream_t stream) {
  const float* x      = (const float*)d_in[0];  // [8192][768] fp32
  const float* w_attn = (const float*)d_in[1];  // [768][2304] fp32
  const float* b_attn = (const float*)d_in[2];  // [2304] fp32
  const float* w_proj = (const float*)d_in[3];  // [768][768] fp32
  const float* b_proj = (const float*)d_in[4];  // [768] fp32
  float* out = (float*)d_out;                   // [8192][768] fp32

  char* ws = (char*)d_ws;
  u16* xb   = (u16*)ws; ws += (size_t)8192 * 768 * 2;     // 12.6 MB
  u16* wTa  = (u16*)ws; ws += (size_t)2304 * 768 * 2;     //  3.5 MB
  u16* wTp  = (u16*)ws; ws += (size_t)768 * 768 * 2;      //  1.2 MB
  u16* qk   = (u16*)ws; ws += (size_t)8192 * 1536 * 2;    // 25.2 MB (Q|K)
  u16* vT   = (u16*)ws; ws += (size_t)96 * 64 * 1024 * 2; // 12.6 MB (V^T)
  u16* yatt = (u16*)ws; ws += (size_t)8192 * 768 * 2;     // 12.6 MB

  // fused prep: x->bf16 + both weight transposes
  prep<<<dim3(6720), 256, 0, stream>>>(x, xb, w_attn, wTa, w_proj, wTp);

  // qkv GEMM: 256x288 tiles, grid 256 = exactly 1 block/CU (XCD-swizzled)
  gemm_qkv_288<<<dim3(256), 768, 0, stream>>>(xb, wTa, b_attn, qk, vT);

  // flash attention (V pre-transposed; in-register softmax)
  attn_fwd<<<dim3(96, 16), 256, 0, stream>>>(qk, vT, yatt);

  // out = yatt @ w_proj + b_proj   (fp32 out, 128x128 tiles)
  gemm_bt_bias<float, 128, false><<<dim3(6, 64), 256, 0, stream>>>(
      yatt, wTp, b_proj, out, (u16*)nullptr, 8192, 768, 768, 768);
}

// Round 4
// 188.848 us; speedup vs baseline: 1.1434x; 1.0416x over previous
//
#include <hip/hip_runtime.h>
#include <hip/hip_bf16.h>
#include <stdint.h>

typedef unsigned short u16;
typedef short short8 __attribute__((ext_vector_type(8)));
typedef short short4v __attribute__((ext_vector_type(4)));
typedef float floatx4 __attribute__((ext_vector_type(4)));

__device__ __forceinline__ float b2f(u16 v) {
  union { unsigned int u; float f; } c; c.u = ((unsigned int)v) << 16; return c.f;
}
__device__ __forceinline__ u16 f2b(float f) {
  union { float f; unsigned int u; } c; c.f = f;
  unsigned int u = c.u;
  return (u16)((u + 0x7fffu + ((u >> 16) & 1u)) >> 16);  // RNE
}

// async global->LDS, 16B per lane. LDS dest must be wave-uniform base + lane*16.
__device__ __forceinline__ void gld_lds16(const u16* g, u16* l) {
  __builtin_amdgcn_global_load_lds(
      (const __attribute__((address_space(1))) unsigned int*)g,
      (__attribute__((address_space(3))) unsigned int*)l,
      16, 0, 0);
}

// ---------------------------------------------------------------------------
// Fused prep: x fp32->bf16 (blocks 0..6143), w_attn T (6144..6575),
// w_proj T (6576..6719). Transposes also convert fp32->bf16.
// ---------------------------------------------------------------------------
__device__ __forceinline__ void tile_transpose_f2b(
    const float* __restrict__ in, u16* __restrict__ out,
    int inRS, int outRS, int rb, int cb, int tid)
{
  __shared__ __align__(16) u16 t[64][72];
  const int r = tid >> 2, sg = tid & 3;
  const float* ip = in + (long)(rb + r) * inRS + cb + sg * 16;
#pragma unroll
  for (int i = 0; i < 16; i += 4) {
    float4 f = *(const float4*)(ip + i);
    t[r][sg * 16 + i]     = f2b(f.x);
    t[r][sg * 16 + i + 1] = f2b(f.y);
    t[r][sg * 16 + i + 2] = f2b(f.z);
    t[r][sg * 16 + i + 3] = f2b(f.w);
  }
  __syncthreads();
  short8 v0, v1;
#pragma unroll
  for (int i = 0; i < 8; i++) v0[i] = (short)t[sg * 16 + i][r];
#pragma unroll
  for (int i = 0; i < 8; i++) v1[i] = (short)t[sg * 16 + 8 + i][r];
  *(short8*)(out + (long)(cb + r) * outRS + rb + sg * 16)     = v0;
  *(short8*)(out + (long)(cb + r) * outRS + rb + sg * 16 + 8) = v1;
}

__global__ __launch_bounds__(256) void prep(
    const float* __restrict__ x, u16* __restrict__ xb,
    const float* __restrict__ w_attn, u16* __restrict__ wTa,
    const float* __restrict__ w_proj, u16* __restrict__ wTp)
{
  const int bid = blockIdx.x, tid = threadIdx.x;
  if (bid < 6144) {
    int i = (bid * 256 + tid) * 4;
    float4 f = *(const float4*)(x + i);
    short4v v;
    v[0] = (short)f2b(f.x); v[1] = (short)f2b(f.y);
    v[2] = (short)f2b(f.z); v[3] = (short)f2b(f.w);
    *(short4v*)(xb + i) = v;
  } else if (bid < 6576) {
    int t = bid - 6144;                 // 36 x 12 tiles of w_attn [768][2304]
    tile_transpose_f2b(w_attn, wTa, 2304, 768, (t / 36) * 64, (t % 36) * 64, tid);
  } else {
    int t = bid - 6576;                 // 12 x 12 tiles of w_proj [768][768]
    tile_transpose_f2b(w_proj, wTp, 768, 768, (t / 12) * 64, (t % 12) * 64, tid);
  }
}

// ---------------------------------------------------------------------------
// Legacy C = A * Bt^T + bias (used for the proj GEMM, 128x128 tiles).
// ---------------------------------------------------------------------------
__device__ __forceinline__ void store_out(u16* p, float v)  { *p = f2b(v); }
__device__ __forceinline__ void store_out(float* p, float v) { *p = v; }

template <int BM>
__device__ __forceinline__ void stage(
    const u16* __restrict__ A, const u16* __restrict__ Bt,
    long rowbase, long colbase, int K, int k0,
    u16* dA, u16* dB, int tid)
{
  const int c0 = tid, c1 = tid + 256;
  const int ar0 = c0 >> 2, ak0 = (c0 & 3) * 8;
  const int ar1 = c1 >> 2, ak1 = (c1 & 3) * 8;
  gld_lds16(A + (rowbase + ar0) * K + k0 + ak0, dA + c0 * 8);
  if (BM == 128)
    gld_lds16(A + (rowbase + ar1) * K + k0 + ak1, dA + c1 * 8);
  gld_lds16(Bt + (colbase + ar0) * K + k0 + ak0, dB + c0 * 8);
  gld_lds16(Bt + (colbase + ar1) * K + k0 + ak1, dB + c1 * 8);
}

template <typename OT, int BM, bool SPLIT>
__global__ __launch_bounds__(256) void gemm_bt_bias(
    const u16* __restrict__ A, const u16* __restrict__ Bt,
    const float* __restrict__ bias, OT* __restrict__ C, u16* __restrict__ vT,
    int M, int N, int K, int strideC)
{
  constexpr int WNF = (BM == 128) ? 4 : 2;      // n-frags per wave
  __shared__ __align__(16) u16 sA[2][BM * 32];
  __shared__ __align__(16) u16 sB[2][128 * 32];
  const int tid = threadIdx.x;
  const int lane = tid & 63;
  const int wave = tid >> 6;
  const int wm = (BM == 128) ? (wave >> 1) * 64 : 0;
  const int wn = (BM == 128) ? (wave & 1) * 64 : wave * 32;
  const int l15 = lane & 15;
  const int q = lane >> 4;
  const long rowbase = (long)blockIdx.y * BM;
  const long colbase = (long)blockIdx.x * 128;

  floatx4 acc[4][WNF];
#pragma unroll
  for (int i = 0; i < 4; i++)
#pragma unroll
    for (int j = 0; j < WNF; j++) acc[i][j] = (floatx4){0.f, 0.f, 0.f, 0.f};

  stage<BM>(A, Bt, rowbase, colbase, K, 0, sA[0], sB[0], tid);
  __syncthreads();   // buf0 ready

  const int NIT = K / 32;
  for (int it = 0; it < NIT; ++it) {
    const int cur = it & 1;
    if (it + 1 < NIT)
      stage<BM>(A, Bt, rowbase, colbase, K, (it + 1) * 32, sA[cur ^ 1], sB[cur ^ 1], tid);
    short8 af[4], bf[WNF];
#pragma unroll
    for (int mt = 0; mt < 4; mt++)
      af[mt] = *(const short8*)(sA[cur] + (wm + mt * 16 + l15) * 32 + q * 8);
#pragma unroll
    for (int nt = 0; nt < WNF; nt++)
      bf[nt] = *(const short8*)(sB[cur] + (wn + nt * 16 + l15) * 32 + q * 8);
#pragma unroll
    for (int mt = 0; mt < 4; mt++)
#pragma unroll
      for (int nt = 0; nt < WNF; nt++)
        acc[mt][nt] = __builtin_amdgcn_mfma_f32_16x16x32_bf16(af[mt], bf[nt], acc[mt][nt], 0, 0, 0);
    if (it + 1 < NIT) __syncthreads();
  }

  if (SPLIT && colbase >= 1536) {
    const long b = rowbase >> 10;
    const int t0b = (int)(rowbase & 1023) + wm;
#pragma unroll
    for (int nt = 0; nt < WNF; nt++) {
      const int col = (int)colbase + wn + nt * 16 + l15;
      const float bv = bias[col];
      const int dloc = col - 1536;
      u16* bp = vT + (b * 12 + (dloc >> 6)) * 65536L + (long)(dloc & 63) * 1024;
#pragma unroll
      for (int mt = 0; mt < 4; mt++) {
        short4v pv;
#pragma unroll
        for (int r = 0; r < 4; r++) pv[r] = (short)f2b(acc[mt][nt][r] + bv);
        *(short4v*)(bp + t0b + mt * 16 + q * 4) = pv;
      }
    }
  } else {
#pragma unroll
    for (int nt = 0; nt < WNF; nt++) {
      const long col = colbase + wn + nt * 16 + l15;
      const float bv = bias[col];
#pragma unroll
      for (int mt = 0; mt < 4; mt++)
#pragma unroll
        for (int r = 0; r < 4; r++) {
          const long row = rowbase + wm + mt * 16 + q * 4 + r;
          store_out(C + row * strideC + col, acc[mt][nt][r] + bv);
        }
    }
  }
}

// ---------------------------------------------------------------------------
// qkv GEMM (R10 geometry, R11: mid-phase alignment barrier removed — it only
// enforced lockstep; slot-reuse safety comes from the boundary barrier).
// Tile 256x288, BK=32, 4 LDS slots, 768 thr = 12 waves (2M x 6N), grid 256.
// ---------------------------------------------------------------------------
#define QKV_K 768
#define QKV_NT 24   // 768/32
#define VMW(n) asm volatile("s_waitcnt vmcnt(" #n ")" ::: "memory")

__global__ __launch_bounds__(768, 3) void gemm_qkv_288(
    const u16* __restrict__ A, const u16* __restrict__ Bt,
    const float* __restrict__ bias, u16* __restrict__ qkOut, u16* __restrict__ vT)
{
  __shared__ __align__(16) u16 sA[4][256 * 32];   // 64 KiB
  __shared__ __align__(16) u16 sB[4][288 * 32];   // 72 KiB

  const int bid = blockIdx.x;
  const int wg = (bid & 7) * 32 + (bid >> 3);
  const int bx = wg & 7;        // col tile 0..7 (288 cols each)
  const int by = wg >> 3;       // row tile 0..31 (256 rows each)

  const int tid = threadIdx.x;
  const int lane = tid & 63;
  const int l15 = lane & 15, q = lane >> 4;
  const int wave = tid >> 6;          // 0..11
  const int wm = (wave / 6) * 128;    // 2 M-groups
  const int wn = (wave % 6) * 48;     // 6 N-groups (3 frags each)
  const long rowbase = (long)by * 256;
  const long colbase = (long)bx * 288;
  // swizzled k-octet offset for frag reads (u16 units)
  const int xq = ((q ^ ((l15 >> 1) & 3)) << 3);

  // staging chunk c (16B): LDS row = c>>2, octet = c&3;
  // pre-swizzled global k-octet = (c&3) ^ ((c>>3)&3)
  const int cA0 = tid, cA1 = 768 + tid;   // A: 1024 chunks (waves 0-3 take 2nd)
  const int cB0 = tid, cB1 = 768 + tid;   // B: 1152 chunks (waves 0-5 take 2nd)
  const u16* pa0 = A + (rowbase + (cA0 >> 2)) * QKV_K + ((((cA0 & 3) ^ ((cA0 >> 3) & 3))) << 3);
  const u16* pa1 = A + (rowbase + (cA1 >> 2)) * QKV_K + ((((cA1 & 3) ^ ((cA1 >> 3) & 3))) << 3);
  const u16* pb0 = Bt + (colbase + (cB0 >> 2)) * QKV_K + ((((cB0 & 3) ^ ((cB0 >> 3) & 3))) << 3);
  const u16* pb1 = Bt + (colbase + (cB1 >> 2)) * QKV_K + ((((cB1 & 3) ^ ((cB1 >> 3) & 3))) << 3);
  const bool hasA1 = (tid < 256);   // wave-uniform
  const bool hasB1 = (tid < 384);   // wave-uniform

#define STAGE(t, s) do { \
    const long k0_ = (long)(t) * 32; \
    gld_lds16(pa0 + k0_, &sA[s][cA0 * 8]); \
    if (hasA1) gld_lds16(pa1 + k0_, &sA[s][cA1 * 8]); \
    gld_lds16(pb0 + k0_, &sB[s][cB0 * 8]); \
    if (hasB1) gld_lds16(pb1 + k0_, &sB[s][cB1 * 8]); } while (0)

  floatx4 acc[8][3];
#pragma unroll
  for (int i = 0; i < 8; i++)
#pragma unroll
    for (int n = 0; n < 3; n++) acc[i][n] = (floatx4){0.f, 0.f, 0.f, 0.f};

  // prologue: tiles 0,1,2 -> slots 0,1,2; wait for own tile-0 loads
  STAGE(0, 0); STAGE(1, 1); STAGE(2, 2);
  if (wave < 4) VMW(8); else if (wave < 6) VMW(6); else VMW(4);
  __builtin_amdgcn_s_barrier();   // all waves' tile-0 resident

#pragma unroll 4
  for (int j = 0; j < QKV_NT; ++j) {
    const int slot = j & 3;
    const u16* ap = sA[slot];
    const u16* bp = sB[slot];

    // ---- phase A: 7 ds_reads, stage tile j+3, 12 MFMA ----
    short8 bf[3];
#pragma unroll
    for (int nt = 0; nt < 3; nt++)
      bf[nt] = *(const short8*)(bp + (wn + nt * 16 + l15) * 32 + xq);
    short8 af[4];
#pragma unroll
    for (int mt = 0; mt < 4; mt++)
      af[mt] = *(const short8*)(ap + (wm + mt * 16 + l15) * 32 + xq);
    if (j + 3 < QKV_NT) STAGE(j + 3, (j + 3) & 3);
    __builtin_amdgcn_s_setprio(1);
#pragma unroll
    for (int mt = 0; mt < 4; mt++)
#pragma unroll
      for (int nt = 0; nt < 3; nt++)
        acc[mt][nt] = __builtin_amdgcn_mfma_f32_16x16x32_bf16(af[mt], bf[nt], acc[mt][nt], 0, 0, 0);
    __builtin_amdgcn_s_setprio(0);

    // ---- phase B: 4 ds_reads, 12 MFMA ----
#pragma unroll
    for (int mt = 0; mt < 4; mt++)
      af[mt] = *(const short8*)(ap + (wm + 64 + mt * 16 + l15) * 32 + xq);
    __builtin_amdgcn_s_setprio(1);
#pragma unroll
    for (int mt = 0; mt < 4; mt++)
#pragma unroll
      for (int nt = 0; nt < 3; nt++)
        acc[4 + mt][nt] = __builtin_amdgcn_mfma_f32_16x16x32_bf16(af[mt], bf[nt], acc[4 + mt][nt], 0, 0, 0);
    __builtin_amdgcn_s_setprio(0);

    // ---- boundary: tile j+1 must be resident; counted waits, wave-uniform ----
    if (j < QKV_NT - 1) {
      if (j + 3 < QKV_NT) {        // 2 tiles outstanding after wait
        if (wave < 4) VMW(8); else if (wave < 6) VMW(6); else VMW(4);
      } else if (j + 2 < QKV_NT) { // 1 tile outstanding after wait
        if (wave < 4) VMW(4); else if (wave < 6) VMW(3); else VMW(2);
      } else {
        VMW(0);                    // 2-tile tail: full drain ok
      }
      __builtin_amdgcn_s_barrier();
    }
  }
#undef STAGE

  // ---- epilogue: per-fragment split at col 1536 (16-aligned inside bx=5) ----
#pragma unroll
  for (int nt = 0; nt < 3; nt++) {
    const int fragc = (int)colbase + wn + nt * 16;   // lane-invariant, 16-aligned
    const int col = fragc + l15;
    const float bv = bias[col];
    if (fragc >= 1536) {
      const long bb = rowbase >> 10;
      const int dloc = col - 1536;
      u16* op = vT + (bb * 12 + (dloc >> 6)) * 65536L + (long)(dloc & 63) * 1024;
      const int t0 = (int)(rowbase & 1023) + wm;
#pragma unroll
      for (int mt = 0; mt < 8; mt++) {
        short4v pv;
#pragma unroll
        for (int r = 0; r < 4; r++) pv[r] = (short)f2b(acc[mt][nt][r] + bv);
        *(short4v*)(op + t0 + mt * 16 + q * 4) = pv;
      }
    } else {
#pragma unroll
      for (int mt = 0; mt < 8; mt++)
#pragma unroll
        for (int r = 0; r < 4; r++) {
          const long row = rowbase + wm + mt * 16 + q * 4 + r;
          qkOut[row * 1536 + col] = f2b(acc[mt][nt][r] + bv);
        }
    }
  }
}
#undef VMW

// ---------------------------------------------------------------------------
// R11 flash attention, causal. One block = (b*12+h, q-tile of 128 rows),
// 512 thr = 8 waves (16 q-rows each). KV tiles of 64 keys.
//   - T14 async-STAGE: K/V(j+1) global loads issued at top of iter j (regs),
//     ds_write after the mid-barrier -> HBM/L2 latency hidden under QK+softmax.
//   - triangle skip: wave-uniform `active` predicate skips QK/softmax/PV for
//     fully-masked tiles (recovers causal-triangle waste of the wide Q-tile).
//   - sK single-buffered: writes sit between mid-sync and bottom-sync;
//     QK reads of the new tile happen after bottom-sync.  sV double-buffered
//     (PV(j) reads sV[j&1] while sV[(j+1)&1] is written).  sP(j+1) writes
//     happen after bottom-sync(j), PV(j) reads before it.
// LDS: (64 + 2*64 + 128) * 72 * 2B = 45 KiB -> 3 blocks/CU (24 waves/CU).
// Grid 96 x 8 = 768 blocks = exactly 3/CU.
// ---------------------------------------------------------------------------
__global__ __launch_bounds__(512) void attn_fwd(
    const u16* __restrict__ qk, const u16* __restrict__ vT, u16* __restrict__ y)
{
  const int bh = blockIdx.x;        // b*12 + h
  const int qt = 7 - blockIdx.y;    // reversed: long blocks dispatch first
  const int b = bh / 12, h = bh % 12;
  const long rowOff = (long)b * 1024;
  const int qb = qt * 128;

  __shared__ __align__(16) u16 sK[64 * 72];
  __shared__ __align__(16) u16 sV[2][64 * 72];  // V^T [d][key], double-buffered
  __shared__ __align__(16) u16 sP[128 * 72];    // P [qrow][key]

  const int tid = threadIdx.x;
  const int lane = tid & 63, wave = tid >> 6;   // 8 waves
  const int l15 = lane & 15, q = lane >> 4;
  const int qrow_l = wave * 16 + l15;           // local q-row 0..127
  const int qrow_g = qb + qrow_l;
  const int wave_max_row = qb + wave * 16 + 15; // wave-uniform

  // staging coords: 512 threads cover a 64x64 bf16 tile (8 thr/row, short8)
  const int sr = tid >> 3, sc = (tid & 7) * 8;
  const u16* kBase = qk + rowOff * 1536 + 768 + (long)h * 64;  // K rows, stride 1536
  const u16* vBase = vT + (long)bh * 65536;                    // V^T rows d, stride 1024

  // Q fragments in registers, pre-scaled by 1/8 (B-operand: n=l15, k=q*8+j)
  short8 qf[2];
  {
    const u16* qp = qk + (long)(rowOff + qrow_g) * 1536 + h * 64 + q * 8;
    short8 a0 = *(const short8*)(qp);
    short8 a1 = *(const short8*)(qp + 32);
#pragma unroll
    for (int i = 0; i < 8; i++) {
      a0[i] = (short)f2b(b2f((u16)a0[i]) * 0.125f);
      a1[i] = (short)f2b(b2f((u16)a1[i]) * 0.125f);
    }
    qf[0] = a0; qf[1] = a1;
  }

  float m_i = -1e30f, l_i = 0.f;
  floatx4 o[4];
#pragma unroll
  for (int nt = 0; nt < 4; nt++) o[nt] = (floatx4){0.f, 0.f, 0.f, 0.f};

  const int J = 2 * qt + 1;   // last KV-tile index

  // prologue: tile 0 -> sK, sV[0]
  *(short8*)(sK + sr * 72 + sc)    = *(const short8*)(kBase + (long)sr * 1536 + sc);
  *(short8*)(sV[0] + sr * 72 + sc) = *(const short8*)(vBase + (long)sr * 1024 + sc);
  __syncthreads();

  for (int j = 0; j <= J; j++) {
    const int jb = j * 64;
    const bool active = (jb <= wave_max_row);   // wave-uniform triangle skip
    const u16* sVc = sV[j & 1];

    // T14: issue next tile's global loads NOW (latency hides under QK+softmax)
    short8 rk = {}, rv = {};
    if (j < J) {
      rk = *(const short8*)(kBase + (long)(jb + 64 + sr) * 1536 + sc);
      rv = *(const short8*)(vBase + (long)sr * 1024 + (jb + 64) + sc);
    }

    float al = 1.f;
    if (active) {
      // S^T = K (Q/8)^T : fragments mt over 16-key blocks
      floatx4 sf[4];
#pragma unroll
      for (int mt = 0; mt < 4; mt++) sf[mt] = (floatx4){0.f, 0.f, 0.f, 0.f};
#pragma unroll
      for (int kk = 0; kk < 2; kk++) {
#pragma unroll
        for (int mt = 0; mt < 4; mt++) {
          short8 kf = *(const short8*)(sK + (mt * 16 + l15) * 72 + kk * 32 + q * 8);
          sf[mt] = __builtin_amdgcn_mfma_f32_16x16x32_bf16(kf, qf[kk], sf[mt], 0, 0, 0);
        }
      }

      // causal mask + in-register online softmax (row = l15-qrow)
      float mx = m_i;
#pragma unroll
      for (int mt = 0; mt < 4; mt++)
#pragma unroll
        for (int r = 0; r < 4; r++) {
          int key_g = jb + mt * 16 + q * 4 + r;
          float v = sf[mt][r];
          if (key_g > qrow_g) v = -1e30f;
          sf[mt][r] = v;
          mx = fmaxf(mx, v);
        }
      mx = fmaxf(mx, __shfl_xor(mx, 16));
      mx = fmaxf(mx, __shfl_xor(mx, 32));
      al = __expf(m_i - mx);
      m_i = mx;
      float rsum = 0.f;
#pragma unroll
      for (int mt = 0; mt < 4; mt++) {
        short4v pv;
#pragma unroll
        for (int r = 0; r < 4; r++) {
          float p = __expf(sf[mt][r] - mx);
          rsum += p;
          pv[r] = (short)f2b(p);
        }
        *(short4v*)(sP + qrow_l * 72 + mt * 16 + q * 4) = pv;
      }
      rsum += __shfl_xor(rsum, 16);
      rsum += __shfl_xor(rsum, 32);
      l_i = l_i * al + rsum;
    }
    __syncthreads();   // sP visible; all QK reads of sK(j) done

    // write next tile to LDS (after the barrier; loads long since landed)
    if (j < J) {
      *(short8*)(sK + sr * 72 + sc)            = rk;
      *(short8*)(sV[(j + 1) & 1] + sr * 72 + sc) = rv;
    }

    if (active) {
      // O = O*alpha + P V   (o rows are q*4+r -> fetch alpha from lane q*4+r)
      float al_r[4];
#pragma unroll
      for (int r = 0; r < 4; r++) al_r[r] = __shfl(al, q * 4 + r);
#pragma unroll
      for (int nt = 0; nt < 4; nt++)
#pragma unroll
        for (int r = 0; r < 4; r++) o[nt][r] *= al_r[r];
#pragma unroll
      for (int kk = 0; kk < 2; kk++) {
        short8 pf = *(const short8*)(sP + qrow_l * 72 + kk * 32 + q * 8);
#pragma unroll
        for (int nt = 0; nt < 4; nt++) {
          short8 vf = *(const short8*)(sVc + (nt * 16 + l15) * 72 + kk * 32 + q * 8);
          o[nt] = __builtin_amdgcn_mfma_f32_16x16x32_bf16(pf, vf, o[nt], 0, 0, 0);
        }
      }
    }
    __syncthreads();   // sK(j+1)/sV writes done before QK(j+1); sP(j) reads done
  }

  float linv = 1.f / l_i;
  float li_r[4];
#pragma unroll
  for (int r = 0; r < 4; r++) li_r[r] = __shfl(linv, q * 4 + r);
#pragma unroll
  for (int nt = 0; nt < 4; nt++)
#pragma unroll
    for (int r = 0; r < 4; r++) {
      int row = qb + wave * 16 + q * 4 + r;
      int col = h * 64 + nt * 16 + l15;
      y[(rowOff + row) * 768 + col] = f2b(o[nt][r] * li_r[r]);
    }
}

// ---------------------------------------------------------------------------
extern "C" void kernel_launch(void* const* d_in, const int* in_sizes, int n_in,
                              void* d_out, int out_size, void* d_ws, size_t ws_size,
                              hipStream_t stream) {
  const float* x      = (const float*)d_in[0];  // [8192][768] fp32
  const float* w_attn = (const float*)d_in[1];  // [768][2304] fp32
  const float* b_attn = (const float*)d_in[2];  // [2304] fp32
  const float* w_proj = (const float*)d_in[3];  // [768][768] fp32
  const float* b_proj = (const float*)d_in[4];  // [768] fp32
  float* out = (float*)d_out;                   // [8192][768] fp32

  char* ws = (char*)d_ws;
  u16* xb   = (u16*)ws; ws += (size_t)8192 * 768 * 2;     // 12.6 MB
  u16* wTa  = (u16*)ws; ws += (size_t)2304 * 768 * 2;     //  3.5 MB
  u16* wTp  = (u16*)ws; ws += (size_t)768 * 768 * 2;      //  1.2 MB
  u16* qk   = (u16*)ws; ws += (size_t)8192 * 1536 * 2;    // 25.2 MB (Q|K)
  u16* vT   = (u16*)ws; ws += (size_t)96 * 64 * 1024 * 2; // 12.6 MB (V^T)
  u16* yatt = (u16*)ws; ws += (size_t)8192 * 768 * 2;     // 12.6 MB

  // fused prep: x->bf16 + both weight transposes
  prep<<<dim3(6720), 256, 0, stream>>>(x, xb, w_attn, wTa, w_proj, wTp);

  // qkv GEMM: 256x288 tiles, grid 256 = exactly 1 block/CU (XCD-swizzled)
  gemm_qkv_288<<<dim3(256), 768, 0, stream>>>(xb, wTa, b_attn, qk, vT);

  // flash attention: 128-row Q-tiles, 8 waves, async-staged K/V
  attn_fwd<<<dim3(96, 8), 512, 0, stream>>>(qk, vT, yatt);

  // out = yatt @ w_proj + b_proj   (fp32 out, 128x128 tiles)
  gemm_bt_bias<float, 128, false><<<dim3(6, 64), 256, 0, stream>>>(
      yatt, wTp, b_proj, out, (u16*)nullptr, 8192, 768, 768, 768);
}